// Round 15
// baseline (4580.419 us; speedup 1.0000x reference)
//
#include <hip/hip_runtime.h>
#include <cstdio>
#include <cstdint>

#define S8     8
#define TENC   12
#define HDIM   256
#define FDIM   316
#define FPAD   320          // x padded feature dim (bf16, zero-filled 316..319)
#define BATCH  1024
#define LDEC   48
#define DBT    32           // batch rows per block in rec_phase; grid 256 = 1 block/CU
#define KA     264          // hA row stride in shorts (16B-aligned rows)
#define SCALE_ATTN 0.0625f  // 1/sqrt(256)

typedef short bf16x8 __attribute__((ext_vector_type(8)));
typedef float f32x4  __attribute__((ext_vector_type(4)));

__device__ __forceinline__ float sigf(float x) { return 1.0f / (1.0f + expf(-x)); }

__device__ __forceinline__ unsigned short f2bf(float f) {
  unsigned u = __builtin_bit_cast(unsigned, f);
  unsigned r = (u + 0x7fffu + ((u >> 16) & 1u)) >> 16;   // RNE
  return (unsigned short)r;
}
__device__ __forceinline__ float bflo(unsigned u) {
  return __builtin_bit_cast(float, u << 16);
}
__device__ __forceinline__ float bfhi(unsigned u) {
  return __builtin_bit_cast(float, u & 0xffff0000u);
}

#define MFMA(acc, a, b) acc = __builtin_amdgcn_mfma_f32_16x16x32_bf16(a, b, acc, 0, 0, 0)

// DOT8: q = 4 u32 holding 8 bf16 (lo/hi pairs), hp = 8 floats
#define DOT8(a, q, hp) \
  a = fmaf(bflo(q.x), hp[0], a); a = fmaf(bfhi(q.x), hp[1], a); \
  a = fmaf(bflo(q.y), hp[2], a); a = fmaf(bfhi(q.y), hp[3], a); \
  a = fmaf(bflo(q.z), hp[4], a); a = fmaf(bfhi(q.z), hp[5], a); \
  a = fmaf(bflo(q.w), hp[6], a); a = fmaf(bfhi(q.w), hp[7], a);

// UNPS: 4 u32 (= 8 ushorts of a bf16 array) -> 8 floats
#define UNPS(dst, off, q) \
  dst[off+0] = bflo(q.x); dst[off+1] = bfhi(q.x); \
  dst[off+2] = bflo(q.y); dst[off+3] = bfhi(q.y); \
  dst[off+4] = bflo(q.z); dst[off+5] = bfhi(q.z); \
  dst[off+6] = bflo(q.w); dst[off+7] = bfhi(q.w);

// ---------------- transpose: in [S][R][C] -> out [S][C][R] ----------------
__global__ __launch_bounds__(256) void transpose_k(const float* __restrict__ in,
                                                   float* __restrict__ out,
                                                   int R, int C) {
  __shared__ float tile[32][33];
  const int s = blockIdx.z;
  const size_t base = (size_t)s * R * C;
  const int r0 = blockIdx.y * 32, c0 = blockIdx.x * 32;
  const int tx = threadIdx.x & 31, ty = threadIdx.x >> 5;
  for (int i = ty; i < 32; i += 8) {
    int r = r0 + i, c = c0 + tx;
    if (r < R && c < C) tile[i][tx] = in[base + (size_t)r * C + c];
  }
  __syncthreads();
  for (int i = ty; i < 32; i += 8) {
    int c = c0 + i, r = r0 + tx;
    if (c < C && r < R) out[base + (size_t)c * R + r] = tile[tx][i];
  }
}

// ---- fold GEMM: out[s][r][col] = sum_e A[s][e][r] * B[s][e][col], 256x256, K=256 ----
__global__ __launch_bounds__(256) void fold_gemm(const float* __restrict__ A, size_t sA,
                                                 const float* __restrict__ Bm, size_t sB,
                                                 float* __restrict__ out, size_t sO) {
  const int s = blockIdx.y, r0 = blockIdx.x * 32, col = threadIdx.x;
  A += (size_t)s * sA; Bm += (size_t)s * sB; out += (size_t)s * sO;
  float acc[32] = {};
  for (int e = 0; e < HDIM; ++e) {
    const float bvv = Bm[(size_t)e * HDIM + col];
#pragma unroll
    for (int r = 0; r < 32; ++r) acc[r] = fmaf(A[(size_t)e * HDIM + r0 + r], bvv, acc[r]);
  }
  for (int r = 0; r < 32; ++r) out[(size_t)(r0 + r) * HDIM + col] = acc[r];
}

// ---- pack x: fp32 [B][96][316] -> bf16 hi/lo [B][96][320] (zero-padded) ----
__global__ void pack_x(const float* __restrict__ x,
                       unsigned short* __restrict__ xH,
                       unsigned short* __restrict__ xL) {
  const size_t idx = (size_t)blockIdx.x * 256 + threadIdx.x;
  if (idx >= (size_t)BATCH * 96 * FPAD) return;
  const int k = (int)(idx % FPAD);
  const size_t bt = idx / FPAD;
  float v = 0.f;
  if (k < FDIM) v = x[bt * FDIM + k];
  const unsigned short hi = f2bf(v);
  xH[idx] = hi;
  xL[idx] = f2bf(v - bflo(hi));
}

// ---- pack gate weights [S][1024][Ksrc] into B-fragment layout, hi+lo bf16 ----
__global__ __launch_bounds__(64) void pack_hl(const float* __restrict__ src, int Ksrc, int ksT,
                                              bf16x8* __restrict__ outhi,
                                              bf16x8* __restrict__ outlo) {
  const int s = blockIdx.z, ks = blockIdx.y, nt = blockIdx.x;
  const int lane = threadIdx.x, l15 = lane & 15, quad = lane >> 4;
  const int n = nt * 16 + l15, kb = ks * 32 + quad * 8;
  const float* row = src + ((size_t)s * 1024 + n) * Ksrc;
  union { bf16x8 v; unsigned short e[8]; } h, l;
#pragma unroll
  for (int j = 0; j < 8; ++j) {
    const int k = kb + j;
    const float v = (k < Ksrc) ? row[k] : 0.f;
    const unsigned short hi = f2bf(v);
    h.e[j] = hi;
    l.e[j] = f2bf(v - bflo(hi));
  }
  const size_t idx = (((size_t)s * ksT + ks) * 64 + nt) * 64 + lane;
  outhi[idx] = h.v;
  outlo[idx] = l.v;
}

// ---- pack attention fold matrix P [S][256][256] into B-frag (single bf16), nt 0..15 ----
__global__ __launch_bounds__(64) void pack_s(const float* __restrict__ src, int ntOff,
                                             bf16x8* __restrict__ out) {
  const int s = blockIdx.z, ks = blockIdx.y, nt = blockIdx.x;
  const int lane = threadIdx.x, l15 = lane & 15, quad = lane >> 4;
  const int n = nt * 16 + l15, kb = ks * 32 + quad * 8;
  const float* row = src + ((size_t)s * 256 + n) * 256;
  union { bf16x8 v; unsigned short e[8]; } h;
#pragma unroll
  for (int j = 0; j < 8; ++j) h.e[j] = f2bf(row[kb + j]);
  out[(((size_t)s * 8 + ks) * 32 + ntOff + nt) * 64 + lane] = h.v;
}

// ---- fold vectors: kbv = Wk^T bq ; cbias = Wo bv + b_out ----
__global__ __launch_bounds__(256) void fold_vec2(const float* __restrict__ Win,
                                                 const float* __restrict__ bin,
                                                 const float* __restrict__ Wout,
                                                 const float* __restrict__ bout,
                                                 float* __restrict__ kbv,
                                                 float* __restrict__ cbias) {
  const int s = blockIdx.x, t = threadIdx.x;
  const float* bq = bin + s * 768;
  const float* bv = bin + s * 768 + 512;
  float a0 = 0.f, a1 = 0.f;
  for (int e = 0; e < 256; ++e) {
    a0 = fmaf(Win[((size_t)s * 768 + 256 + e) * 256 + t], bq[e], a0);
    a1 = fmaf(Wout[((size_t)s * 256 + t) * 256 + e], bv[e], a1);
  }
  kbv[s * 256 + t] = a0;
  cbias[s * 256 + t] = a1 + bout[s * 256 + t];
}

// ---- mvw[s][k] = sum_o wfo2[s][o] * Mv[s][o][k] ----
__global__ __launch_bounds__(256) void fold_mvw(const float* __restrict__ Mv,
                                                const float* __restrict__ Wfo,
                                                float* __restrict__ mvw) {
  const int s = blockIdx.x, k = threadIdx.x;
  float a = 0.f;
  for (int o = 0; o < 256; ++o)
    a = fmaf(Wfo[s * 512 + 256 + o], Mv[((size_t)s * 256 + o) * 256 + k], a);
  mvw[s * 256 + k] = a;
}

__global__ void fold_bias(const float* __restrict__ a, const float* __restrict__ b,
                          float* __restrict__ o, int n) {
  int i = blockIdx.x * 256 + threadIdx.x;
  if (i < n) o[i] = a[i] + b[i];
}

__global__ void build_decin(const float* __restrict__ x, const float* __restrict__ tgt,
                            float* __restrict__ dec_in) {
  int idx = blockIdx.x * 256 + threadIdx.x;
  if (idx >= LDEC * BATCH) return;
  int l = idx >> 10, b = idx & 1023;
  dec_in[idx] = (l == 0) ? x[(size_t)b * 96 * FDIM + 95 * FDIM]
                         : tgt[(size_t)b * LDEC + (l - 1)];
}

// =============== PHASE A: the recurrence, 1024 threads ===============
// Register model (R12-R14 validated): granted arch VGPR = 65536/threads
// (immovable); MFMA accs add on top; waves/SIMD = floor(512/(arch+acc)).
// 1024 thr -> 64 arch + 32 acc = 96 -> 4 waves/SIMD = 16 waves/CU (~48%),
// double R14's occupancy. Demand must fit 64: x PRE-CONVERTED to bf16 hi/lo
// (pack_x) so A-frags load directly (no fp32->bf16 staging temps), biases in
// LDS, one col per thread (JJ = 16w+l15): frags 16 + hv/cst 16 + addrs ~25.
// grid 256 = 1 block/CU, one dispatch round, XCD = bid%8 pins stream weights.
__global__ __launch_bounds__(1024) void rec_phase(
    const unsigned short* __restrict__ xH, const unsigned short* __restrict__ xL,
    const bf16x8* __restrict__ WxH, const bf16x8* __restrict__ WxL,
    const bf16x8* __restrict__ WeH, const bf16x8* __restrict__ WeL,
    const bf16x8* __restrict__ WdH, const bf16x8* __restrict__ WdL,
    const float* __restrict__ be, const float* __restrict__ bd,
    const float* __restrict__ wihd, const float* __restrict__ Wfo,
    const float* __restrict__ decin,
    unsigned* __restrict__ hEnc,         // [t][s][b][e] packed hi|lo
    unsigned short* __restrict__ hDec,   // [l][s][b][e] bf16 hi
    float* __restrict__ hdPart)          // [l][s][b] = h_dec . wfo1 (fp32)
{
  __shared__ unsigned short hAhi[DBT * KA];   // 16.9 KB
  __shared__ unsigned short hAlo[DBT * KA];   // 16.9 KB
  __shared__ float beS[1024];                 // 4 KB
  __shared__ float bdS[1024];                 // 4 KB
  __shared__ float wdS[1024];                 // 4 KB
  __shared__ float wfoS[256];                 // 1 KB
  __shared__ float scrR[DBT * 16];            // 2 KB (hd partials, 16 waves)

  const int bid = blockIdx.x;
  const int s = bid & 7, b0 = (bid >> 3) * DBT;
  const int tid = threadIdx.x;
  const int w = tid >> 6, lane = tid & 63, l15 = lane & 15, quad = lane >> 4;
  const int JJ = 16 * w + l15;   // this thread's single col in [0,256)

  for (int i = tid; i < DBT * KA; i += 1024) { hAhi[i] = 0; hAlo[i] = 0; }
  if (tid < 1024) {
    beS[tid] = be[s * 1024 + tid];
    bdS[tid] = bd[s * 1024 + tid];
    wdS[tid] = wihd[s * 1024 + tid];
  }
  if (tid < 256) wfoS[tid] = Wfo[s * 512 + tid];

  float cst[2][4];   // [mt][reg]
#pragma unroll
  for (int a = 0; a < 2; ++a)
#pragma unroll
    for (int r = 0; r < 4; ++r) cst[a][r] = 0.f;

  const bf16x8* wxh = WxH + (size_t)s * 10 * 64 * 64;
  const bf16x8* wxl = WxL + (size_t)s * 10 * 64 * 64;
  const bf16x8* weh = WeH + (size_t)s * 8 * 64 * 64;
  const bf16x8* wel = WeL + (size_t)s * 8 * 64 * 64;
  const bf16x8* wdh = WdH + (size_t)s * 8 * 64 * 64;
  const bf16x8* wdl = WdL + (size_t)s * 8 * 64 * 64;

  __syncthreads();

  // ===================== encoder =====================
  for (int t = 0; t < TENC; ++t) {
    f32x4 acc[2][4];   // [mt][g]
#pragma unroll
    for (int mt = 0; mt < 2; ++mt)
#pragma unroll
      for (int g = 0; g < 4; ++g) acc[mt][g] = (f32x4){0.f, 0.f, 0.f, 0.f};

    const size_t xoff = (size_t)(s * TENC + t) * FPAD;
    // x-part: 10 ksteps, A-frags loaded DIRECTLY as bf16 (pre-converted)
    for (int ks = 0; ks < 10; ++ks) {
      bf16x8 axh[2], axl[2];
#pragma unroll
      for (int mt = 0; mt < 2; ++mt) {
        const size_t ro = (size_t)(b0 + 16 * mt + l15) * (96 * FPAD) + xoff
                        + ks * 32 + quad * 8;
        axh[mt] = *(const bf16x8*)&xH[ro];
        axl[mt] = *(const bf16x8*)&xL[ro];
      }
#pragma unroll
      for (int g = 0; g < 4; ++g) {
        const int nt = g * 16 + w;
        const bf16x8 bh = wxh[(ks * 64 + nt) * 64 + lane];
        const bf16x8 bl = wxl[(ks * 64 + nt) * 64 + lane];
        MFMA(acc[0][g], axh[0], bh); MFMA(acc[0][g], axh[0], bl); MFMA(acc[0][g], axl[0], bh);
        MFMA(acc[1][g], axh[1], bh); MFMA(acc[1][g], axh[1], bl); MFMA(acc[1][g], axl[1], bh);
      }
    }
    // h-part: 8 ksteps, A-frags from LDS
    for (int ks = 0; ks < 8; ++ks) {
      bf16x8 ah[2], al[2];
#pragma unroll
      for (int mt = 0; mt < 2; ++mt) {
        const int ao = (16 * mt + l15) * KA + ks * 32 + quad * 8;
        ah[mt] = *(const bf16x8*)&hAhi[ao];
        al[mt] = *(const bf16x8*)&hAlo[ao];
      }
#pragma unroll
      for (int g = 0; g < 4; ++g) {
        const int nt = g * 16 + w;
        const bf16x8 bh = weh[(ks * 64 + nt) * 64 + lane];
        const bf16x8 bl = wel[(ks * 64 + nt) * 64 + lane];
        MFMA(acc[0][g], ah[0], bh); MFMA(acc[0][g], ah[0], bl); MFMA(acc[0][g], al[0], bh);
        MFMA(acc[1][g], ah[1], bh); MFMA(acc[1][g], ah[1], bl); MFMA(acc[1][g], al[1], bh);
      }
    }
    // pointwise LSTM (one col per thread)
    float hv[2][4];
    {
      const float g0 = beS[JJ];
      const float g1 = beS[256 + JJ];
      const float g2 = beS[512 + JJ];
      const float g3 = beS[768 + JJ];
#pragma unroll
      for (int mt = 0; mt < 2; ++mt)
#pragma unroll
        for (int reg = 0; reg < 4; ++reg) {
          const float gi = sigf(acc[mt][0][reg] + g0);
          const float gf = sigf(acc[mt][1][reg] + g1);
          const float gg = tanhf(acc[mt][2][reg] + g2);
          const float go = sigf(acc[mt][3][reg] + g3);
          const float cn = fmaf(gf, cst[mt][reg], gi * gg);
          cst[mt][reg] = cn;
          hv[mt][reg] = go * tanhf(cn);
        }
    }
    __syncthreads();
#pragma unroll
    for (int mt = 0; mt < 2; ++mt)
#pragma unroll
      for (int reg = 0; reg < 4; ++reg) {
        const int R = 16 * mt + 4 * quad + reg;
        const float v = hv[mt][reg];
        const unsigned short hi = f2bf(v);
        const unsigned short lo = f2bf(v - bflo(hi));
        hAhi[R * KA + JJ] = hi;
        hAlo[R * KA + JJ] = lo;
        __builtin_nontemporal_store((unsigned)hi | ((unsigned)lo << 16),
            &hEnc[((size_t)(t * S8 + s) * BATCH + b0 + R) * HDIM + JJ]);
      }
    __syncthreads();
  }

  // ===================== decoder (LSTM only + fp32 hd dot) =====================
  for (int l = 0; l < LDEC; ++l) {
    f32x4 acc[2][4];
#pragma unroll
    for (int mt = 0; mt < 2; ++mt)
#pragma unroll
      for (int g = 0; g < 4; ++g) acc[mt][g] = (f32x4){0.f, 0.f, 0.f, 0.f};

    for (int ks = 0; ks < 8; ++ks) {
      bf16x8 ah[2], al[2];
#pragma unroll
      for (int mt = 0; mt < 2; ++mt) {
        const int ao = (16 * mt + l15) * KA + ks * 32 + quad * 8;
        ah[mt] = *(const bf16x8*)&hAhi[ao];
        al[mt] = *(const bf16x8*)&hAlo[ao];
      }
#pragma unroll
      for (int g = 0; g < 4; ++g) {
        const int nt = g * 16 + w;
        const bf16x8 bh = wdh[(ks * 64 + nt) * 64 + lane];
        const bf16x8 bl = wdl[(ks * 64 + nt) * 64 + lane];
        MFMA(acc[0][g], ah[0], bh); MFMA(acc[0][g], ah[0], bl); MFMA(acc[0][g], al[0], bh);
        MFMA(acc[1][g], ah[1], bh); MFMA(acc[1][g], ah[1], bl); MFMA(acc[1][g], al[1], bh);
      }
    }
    float hv[2][4];
    {
      const float b0g = bdS[JJ];
      const float b1g = bdS[256 + JJ];
      const float b2g = bdS[512 + JJ];
      const float b3g = bdS[768 + JJ];
      const float w0g = wdS[JJ];
      const float w1g = wdS[256 + JJ];
      const float w2g = wdS[512 + JJ];
      const float w3g = wdS[768 + JJ];
#pragma unroll
      for (int mt = 0; mt < 2; ++mt)
#pragma unroll
        for (int reg = 0; reg < 4; ++reg) {
          const int R = 16 * mt + 4 * quad + reg;
          const float it = decin[(size_t)l * BATCH + b0 + R];
          const float gi = sigf(fmaf(it, w0g, acc[mt][0][reg] + b0g));
          const float gf = sigf(fmaf(it, w1g, acc[mt][1][reg] + b1g));
          const float gg = tanhf(fmaf(it, w2g, acc[mt][2][reg] + b2g));
          const float go = sigf(fmaf(it, w3g, acc[mt][3][reg] + b3g));
          const float cn = fmaf(gf, cst[mt][reg], gi * gg);
          cst[mt][reg] = cn;
          hv[mt][reg] = go * tanhf(cn);
        }
    }
    __syncthreads();
#pragma unroll
    for (int mt = 0; mt < 2; ++mt)
#pragma unroll
      for (int reg = 0; reg < 4; ++reg) {
        const int R = 16 * mt + 4 * quad + reg;
        const float v = hv[mt][reg];
        const unsigned short hi = f2bf(v);
        hAhi[R * KA + JJ] = hi;
        hAlo[R * KA + JJ] = f2bf(v - bflo(hi));
        __builtin_nontemporal_store(hi,
            &hDec[((size_t)(l * S8 + s) * BATCH + b0 + R) * HDIM + JJ]);
      }
    // hd = h . wfo1 in fp32 from registers
    {
      float part[8];
#pragma unroll
      for (int mt = 0; mt < 2; ++mt)
#pragma unroll
        for (int reg = 0; reg < 4; ++reg)
          part[mt * 4 + reg] = hv[mt][reg] * wfoS[JJ];
#pragma unroll
      for (int i = 0; i < 8; ++i) {
        float v = part[i];
        v += __shfl_xor(v, 1, 16);
        v += __shfl_xor(v, 2, 16);
        v += __shfl_xor(v, 4, 16);
        v += __shfl_xor(v, 8, 16);
        part[i] = v;
      }
      if (l15 == 0) {
#pragma unroll
        for (int mt = 0; mt < 2; ++mt)
#pragma unroll
          for (int reg = 0; reg < 4; ++reg)
            scrR[(16 * mt + 4 * quad + reg) * 16 + w] = part[mt * 4 + reg];
      }
    }
    __syncthreads();
    if (tid < DBT) {
      float a = 0.f;
#pragma unroll
      for (int p = 0; p < 16; ++p) a += scrR[tid * 16 + p];
      hdPart[((size_t)l * S8 + s) * BATCH + b0 + tid] = a;
    }
    // no extra barrier: scrR's next write is after next iter's first sync
  }
}

// =============== PHASE B: attention + output, fully parallel ===============
__global__ __launch_bounds__(256) void attn_phase(
    const unsigned* __restrict__ hEnc, const unsigned short* __restrict__ hDec,
    const bf16x8* __restrict__ AMvF,
    const float* __restrict__ kbv, const float* __restrict__ cbias,
    const float* __restrict__ mvw,
    const float* __restrict__ Wfo, const float* __restrict__ bfo,
    const float* __restrict__ hdPart,
    float* __restrict__ douts)
{
  __shared__ unsigned short kpL[TENC][16][KA];  // 101.4 KB
  __shared__ float scr[16 * TENC * 17];         // 13.1 KB
  __shared__ float sc[16][TENC];
  __shared__ float kbs[TENC][16];
  __shared__ float vw[TENC][16];

  const int s = blockIdx.y, b0 = blockIdx.x * 16;
  const int tid = threadIdx.x;
  const int w = tid >> 6, lane = tid & 63, l15 = lane & 15, quad = lane >> 4;

  const bf16x8* amv = AMvF + (size_t)s * 8 * 32 * 64;
  const float* kvv = kbv + s * 256;
  const float* mvv = mvw + s * 256;
  const float* cbs = cbias + s * 256;
  const float* wfo = Wfo + s * 512;
  const float bfos = bfo[s];

  float cw = 0.f;
  for (int e = 0; e < 256; ++e) cw = fmaf(cbs[e], wfo[256 + e], cw);

  // --- kp[t] = P . h_enc[t] via MFMA (hi+lo A); rows via l15, nt = 4w+c ---
  for (int t = 0; t < TENC; ++t) {
    f32x4 acc[4];
#pragma unroll
    for (int c = 0; c < 4; ++c) acc[c] = (f32x4){0.f, 0.f, 0.f, 0.f};
    for (int ks = 0; ks < 8; ++ks) {
      const unsigned* hp = hEnc + ((size_t)(t * S8 + s) * BATCH + b0 + l15) * HDIM
                         + ks * 32 + quad * 8;
      union { bf16x8 v; unsigned short e[8]; } uh, ul;
#pragma unroll
      for (int j = 0; j < 8; ++j) {
        const unsigned u = hp[j];
        uh.e[j] = (unsigned short)u;
        ul.e[j] = (unsigned short)(u >> 16);
      }
#pragma unroll
      for (int c = 0; c < 4; ++c) {
        const int nt = w * 4 + c;
        const bf16x8 b = amv[(ks * 32 + nt) * 64 + lane];
        MFMA(acc[c], uh.v, b); MFMA(acc[c], ul.v, b);
      }
    }
#pragma unroll
    for (int c = 0; c < 4; ++c)
#pragma unroll
      for (int reg = 0; reg < 4; ++reg)
        kpL[t][4 * quad + reg][(w * 4 + c) * 16 + l15] = f2bf(acc[c][reg]);
  }
  // --- kbs / vw folds from h_enc (hi+lo floats) ---
  for (int t = 0; t < TENC; ++t) {
    const int row = tid >> 4, p = tid & 15;
    const unsigned* hp = hEnc + ((size_t)(t * S8 + s) * BATCH + b0 + row) * HDIM + p * 16;
    float a = 0.f, b = 0.f;
#pragma unroll
    for (int k = 0; k < 16; ++k) {
      const unsigned u = hp[k];
      const float h = bflo(u) + bfhi(u);
      a = fmaf(kvv[p * 16 + k], h, a);
      b = fmaf(mvv[p * 16 + k], h, b);
    }
    scr[row * 34 + p] = a;
    scr[row * 34 + 17 + p] = b;
    __syncthreads();
    if (tid < 16) {
      float sa = 0.f, sb = 0.f;
#pragma unroll
      for (int p2 = 0; p2 < 16; ++p2) { sa += scr[tid * 34 + p2]; sb += scr[tid * 34 + 17 + p2]; }
      kbs[t][tid] = sa;
      vw[t][tid] = sb;
    }
    __syncthreads();
  }

  // --- per-l scores/softmax/out ---
  for (int l = 0; l < LDEC; ++l) {
    const int row = tid & 15, pp = tid >> 4;
    float hh[16];
    {
      const unsigned short* hp = hDec + ((size_t)(l * S8 + s) * BATCH + b0 + row) * HDIM + pp * 16;
      const uint4 q0 = *(const uint4*)hp;
      const uint4 q1 = *(const uint4*)(hp + 8);
      UNPS(hh, 0, q0);
      UNPS(hh, 8, q1);
    }
#pragma unroll 2
    for (int t = 0; t < TENC; ++t) {
      const uint4 q0 = *(const uint4*)&kpL[t][row][pp * 16];
      const uint4 q1 = *(const uint4*)&kpL[t][row][pp * 16 + 8];
      float a = 0.f;
      { const float* hp8 = &hh[0]; DOT8(a, q0, hp8); }
      { const float* hp8 = &hh[8]; DOT8(a, q1, hp8); }
      scr[(row * TENC + t) * 17 + pp] = a;
    }
    __syncthreads();
    if (tid < 192) {
      const int r2 = tid & 15, t2 = tid >> 4;
      float a = kbs[t2][r2];
#pragma unroll
      for (int p2 = 0; p2 < 16; ++p2) a += scr[(r2 * TENC + t2) * 17 + p2];
      sc[r2][t2] = a * SCALE_ATTN;
    }
    __syncthreads();
    if (tid < 16) {
      float m = sc[tid][0];
#pragma unroll
      for (int t2 = 1; t2 < TENC; ++t2) m = fmaxf(m, sc[tid][t2]);
      float e[TENC], sum = 0.f;
#pragma unroll
      for (int t2 = 0; t2 < TENC; ++t2) { e[t2] = expf(sc[tid][t2] - m); sum += e[t2]; }
      const float inv = 1.0f / sum;
      float av = 0.f;
#pragma unroll
      for (int t2 = 0; t2 < TENC; ++t2) av = fmaf(e[t2] * inv, vw[t2][tid], av);
      const float hd = hdPart[((size_t)l * S8 + s) * BATCH + b0 + tid];
      douts[((size_t)l * S8 + s) * BATCH + b0 + tid] = hd + av + cw + bfos;
    }
    __syncthreads();
  }
}

// ---------------- final fc over streams ----------------
__global__ void final_fc(const float* __restrict__ douts, const float* __restrict__ Wfc,
                         const float* __restrict__ bfc, float* __restrict__ out) {
  int idx = blockIdx.x * 256 + threadIdx.x;
  if (idx >= BATCH * LDEC) return;
  int b = idx / LDEC, l = idx - b * LDEC;
  float a = bfc[0];
#pragma unroll
  for (int s = 0; s < S8; ++s)
    a = fmaf(douts[((size_t)l * S8 + s) * BATCH + b], Wfc[s], a);
  out[idx] = a;
}

extern "C" void kernel_launch(void* const* d_in, const int* in_sizes, int n_in,
                              void* d_out, int out_size, void* d_ws, size_t ws_size,
                              hipStream_t stream) {
  const float* x          = (const float*)d_in[0];
  const float* tgt        = (const float*)d_in[1];
  const float* W_ih_e     = (const float*)d_in[2];
  const float* W_hh_e     = (const float*)d_in[3];
  const float* b_ih_e     = (const float*)d_in[4];
  const float* b_hh_e     = (const float*)d_in[5];
  const float* W_ih_d     = (const float*)d_in[6];
  const float* W_hh_d     = (const float*)d_in[7];
  const float* b_ih_d     = (const float*)d_in[8];
  const float* b_hh_d     = (const float*)d_in[9];
  const float* W_in_attn  = (const float*)d_in[10];
  const float* b_in_attn  = (const float*)d_in[11];
  const float* W_out_attn = (const float*)d_in[12];
  const float* b_out_attn = (const float*)d_in[13];
  const float* W_fcout    = (const float*)d_in[14];
  const float* b_fcout    = (const float*)d_in[15];
  const float* W_fc       = (const float*)d_in[16];
  const float* b_fc       = (const float*)d_in[17];

  char* wsb = (char*)d_ws;
  size_t off = 0;
  auto alloc = [&](size_t bytes) {
    void* p = wsb + off; off += (bytes + 255) & ~(size_t)255; return p;
  };
  float*  douts = (float*)alloc((size_t)LDEC * S8 * BATCH * 4);
  float*  decin = (float*)alloc((size_t)LDEC * BATCH * 4);
  float*  hdPart= (float*)alloc((size_t)LDEC * S8 * BATCH * 4);
  float*  Pmat  = (float*)alloc((size_t)S8 * 256 * 256 * 4);
  float*  Mvmat = (float*)alloc((size_t)S8 * 256 * 256 * 4);
  float*  WoT   = (float*)alloc((size_t)S8 * 256 * 256 * 4);
  bf16x8* WxH   = (bf16x8*)alloc((size_t)S8 * 10 * 64 * 64 * 16);
  bf16x8* WxL   = (bf16x8*)alloc((size_t)S8 * 10 * 64 * 64 * 16);
  bf16x8* WeH   = (bf16x8*)alloc((size_t)S8 * 8 * 64 * 64 * 16);
  bf16x8* WeL   = (bf16x8*)alloc((size_t)S8 * 8 * 64 * 64 * 16);
  bf16x8* WdH   = (bf16x8*)alloc((size_t)S8 * 8 * 64 * 64 * 16);
  bf16x8* WdL   = (bf16x8*)alloc((size_t)S8 * 8 * 64 * 64 * 16);
  bf16x8* AMvF  = (bf16x8*)alloc((size_t)S8 * 8 * 32 * 64 * 16);
  float*  kbv   = (float*)alloc((size_t)S8 * 256 * 4);
  float*  cbias = (float*)alloc((size_t)S8 * 256 * 4);
  float*  mvw   = (float*)alloc((size_t)S8 * 256 * 4);
  float*  beF   = (float*)alloc((size_t)S8 * 1024 * 4);
  float*  bdF   = (float*)alloc((size_t)S8 * 1024 * 4);
  unsigned* hEnc = (unsigned*)alloc((size_t)TENC * S8 * BATCH * HDIM * 4);             // 100.7 MB
  unsigned short* hDec = (unsigned short*)alloc((size_t)LDEC * S8 * BATCH * HDIM * 2); // 201.3 MB
  unsigned short* xHb = (unsigned short*)alloc((size_t)BATCH * 96 * FPAD * 2);         // 62.9 MB
  unsigned short* xLb = (unsigned short*)alloc((size_t)BATCH * 96 * FPAD * 2);         // 62.9 MB
  if (off > ws_size) {
    fprintf(stderr, "kernel_launch: ws too small: need %zu bytes, have %zu\n", off, ws_size);
    return;
  }

  // ---- one-time weight/input preparation ----
  transpose_k<<<dim3(8, 8, S8), 256, 0, stream>>>(W_out_attn, WoT, 256, 256);
  fold_gemm<<<dim3(8, S8), 256, 0, stream>>>(W_in_attn, (size_t)768 * 256,
                                             W_in_attn + 256 * 256, (size_t)768 * 256,
                                             Pmat, (size_t)256 * 256);
  fold_gemm<<<dim3(8, S8), 256, 0, stream>>>(WoT, (size_t)256 * 256,
                                             W_in_attn + 2 * 256 * 256, (size_t)768 * 256,
                                             Mvmat, (size_t)256 * 256);
  pack_x<<<(int)(((size_t)BATCH * 96 * FPAD + 255) / 256), 256, 0, stream>>>(x, xHb, xLb);
  pack_hl<<<dim3(64, 10, S8), 64, 0, stream>>>(W_ih_e, FDIM, 10, WxH, WxL);
  pack_hl<<<dim3(64, 8, S8), 64, 0, stream>>>(W_hh_e, 256, 8, WeH, WeL);
  pack_hl<<<dim3(64, 8, S8), 64, 0, stream>>>(W_hh_d, 256, 8, WdH, WdL);
  pack_s<<<dim3(16, 8, S8), 64, 0, stream>>>(Pmat, 0, AMvF);
  fold_vec2<<<S8, 256, 0, stream>>>(W_in_attn, b_in_attn, W_out_attn, b_out_attn, kbv, cbias);
  fold_mvw<<<S8, 256, 0, stream>>>(Mvmat, W_fcout, mvw);
  fold_bias<<<(S8 * 1024 + 255) / 256, 256, 0, stream>>>(b_ih_e, b_hh_e, beF, S8 * 1024);
  fold_bias<<<(S8 * 1024 + 255) / 256, 256, 0, stream>>>(b_ih_d, b_hh_d, bdF, S8 * 1024);
  build_decin<<<(LDEC * BATCH + 255) / 256, 256, 0, stream>>>(x, tgt, decin);

  // Phase A: the recurrence only (grid 256, 1024 thr, 16 waves/CU target)
  rec_phase<<<256, 1024, 0, stream>>>(
      xHb, xLb, WxH, WxL, WeH, WeL, WdH, WdL, beF, bdF, W_ih_d, W_fcout, decin,
      hEnc, hDec, hdPart);

  // Phase B: attention + outputs (fully parallel over l and batch)
  attn_phase<<<dim3(64, S8), 256, 0, stream>>>(
      hEnc, hDec, AMvF, kbv, cbias, mvw, W_fcout, b_fcout, hdPart, douts);

  final_fc<<<(BATCH * LDEC + 255) / 256, 256, 0, stream>>>(douts, W_fc, b_fc, (float*)d_out);
}

// Round 16
// 3457.940 us; speedup vs baseline: 1.3246x; 1.3246x over previous
//
#include <hip/hip_runtime.h>
#include <cstdio>
#include <cstdint>

#define S8     8
#define TENC   12
#define HDIM   256
#define FDIM   316
#define FPAD   320          // x padded feature dim (bf16, zero-filled 316..319)
#define BATCH  1024
#define LDEC   48
#define DBT    32           // batch rows per block in rec_phase; grid 256 = 1 block/CU
#define KA     264          // hA row stride in shorts (16B-aligned rows)
#define SCALE_ATTN 0.0625f  // 1/sqrt(256)

typedef short bf16x8 __attribute__((ext_vector_type(8)));
typedef float f32x4  __attribute__((ext_vector_type(4)));

__device__ __forceinline__ float sigf(float x) { return 1.0f / (1.0f + expf(-x)); }

__device__ __forceinline__ unsigned short f2bf(float f) {
  unsigned u = __builtin_bit_cast(unsigned, f);
  unsigned r = (u + 0x7fffu + ((u >> 16) & 1u)) >> 16;   // RNE
  return (unsigned short)r;
}
__device__ __forceinline__ float bflo(unsigned u) {
  return __builtin_bit_cast(float, u << 16);
}
__device__ __forceinline__ float bfhi(unsigned u) {
  return __builtin_bit_cast(float, u & 0xffff0000u);
}

#define MFMA(acc, a, b) acc = __builtin_amdgcn_mfma_f32_16x16x32_bf16(a, b, acc, 0, 0, 0)

// DOT8: q = 4 u32 holding 8 bf16 (lo/hi pairs), hp = 8 floats
#define DOT8(a, q, hp) \
  a = fmaf(bflo(q.x), hp[0], a); a = fmaf(bfhi(q.x), hp[1], a); \
  a = fmaf(bflo(q.y), hp[2], a); a = fmaf(bfhi(q.y), hp[3], a); \
  a = fmaf(bflo(q.z), hp[4], a); a = fmaf(bfhi(q.z), hp[5], a); \
  a = fmaf(bflo(q.w), hp[6], a); a = fmaf(bfhi(q.w), hp[7], a);

// UNPS: 4 u32 (= 8 ushorts of a bf16 array) -> 8 floats
#define UNPS(dst, off, q) \
  dst[off+0] = bflo(q.x); dst[off+1] = bfhi(q.x); \
  dst[off+2] = bflo(q.y); dst[off+3] = bfhi(q.y); \
  dst[off+4] = bflo(q.z); dst[off+5] = bfhi(q.z); \
  dst[off+6] = bflo(q.w); dst[off+7] = bfhi(q.w);

// ---------------- transpose: in [S][R][C] -> out [S][C][R] ----------------
__global__ __launch_bounds__(256) void transpose_k(const float* __restrict__ in,
                                                   float* __restrict__ out,
                                                   int R, int C) {
  __shared__ float tile[32][33];
  const int s = blockIdx.z;
  const size_t base = (size_t)s * R * C;
  const int r0 = blockIdx.y * 32, c0 = blockIdx.x * 32;
  const int tx = threadIdx.x & 31, ty = threadIdx.x >> 5;
  for (int i = ty; i < 32; i += 8) {
    int r = r0 + i, c = c0 + tx;
    if (r < R && c < C) tile[i][tx] = in[base + (size_t)r * C + c];
  }
  __syncthreads();
  for (int i = ty; i < 32; i += 8) {
    int c = c0 + i, r = r0 + tx;
    if (c < C && r < R) out[base + (size_t)c * R + r] = tile[tx][i];
  }
}

// ---- fold GEMM: out[s][r][col] = sum_e A[s][e][r] * B[s][e][col], 256x256, K=256 ----
__global__ __launch_bounds__(256) void fold_gemm(const float* __restrict__ A, size_t sA,
                                                 const float* __restrict__ Bm, size_t sB,
                                                 float* __restrict__ out, size_t sO) {
  const int s = blockIdx.y, r0 = blockIdx.x * 32, col = threadIdx.x;
  A += (size_t)s * sA; Bm += (size_t)s * sB; out += (size_t)s * sO;
  float acc[32] = {};
  for (int e = 0; e < HDIM; ++e) {
    const float bvv = Bm[(size_t)e * HDIM + col];
#pragma unroll
    for (int r = 0; r < 32; ++r) acc[r] = fmaf(A[(size_t)e * HDIM + r0 + r], bvv, acc[r]);
  }
  for (int r = 0; r < 32; ++r) out[(size_t)(r0 + r) * HDIM + col] = acc[r];
}

// ---- pack x: fp32 [B][96][316] -> bf16 hi/lo [B][96][320] (zero-padded) ----
__global__ void pack_x(const float* __restrict__ x,
                       unsigned short* __restrict__ xH,
                       unsigned short* __restrict__ xL) {
  const size_t idx = (size_t)blockIdx.x * 256 + threadIdx.x;
  if (idx >= (size_t)BATCH * 96 * FPAD) return;
  const int k = (int)(idx % FPAD);
  const size_t bt = idx / FPAD;
  float v = 0.f;
  if (k < FDIM) v = x[bt * FDIM + k];
  const unsigned short hi = f2bf(v);
  xH[idx] = hi;
  xL[idx] = f2bf(v - bflo(hi));
}

// ---- pack gate weights [S][1024][Ksrc] into B-fragment layout, hi+lo bf16 ----
__global__ __launch_bounds__(64) void pack_hl(const float* __restrict__ src, int Ksrc, int ksT,
                                              bf16x8* __restrict__ outhi,
                                              bf16x8* __restrict__ outlo) {
  const int s = blockIdx.z, ks = blockIdx.y, nt = blockIdx.x;
  const int lane = threadIdx.x, l15 = lane & 15, quad = lane >> 4;
  const int n = nt * 16 + l15, kb = ks * 32 + quad * 8;
  const float* row = src + ((size_t)s * 1024 + n) * Ksrc;
  union { bf16x8 v; unsigned short e[8]; } h, l;
#pragma unroll
  for (int j = 0; j < 8; ++j) {
    const int k = kb + j;
    const float v = (k < Ksrc) ? row[k] : 0.f;
    const unsigned short hi = f2bf(v);
    h.e[j] = hi;
    l.e[j] = f2bf(v - bflo(hi));
  }
  const size_t idx = (((size_t)s * ksT + ks) * 64 + nt) * 64 + lane;
  outhi[idx] = h.v;
  outlo[idx] = l.v;
}

// ---- pack attention fold matrix P [S][256][256] into B-frag (single bf16), nt 0..15 ----
__global__ __launch_bounds__(64) void pack_s(const float* __restrict__ src, int ntOff,
                                             bf16x8* __restrict__ out) {
  const int s = blockIdx.z, ks = blockIdx.y, nt = blockIdx.x;
  const int lane = threadIdx.x, l15 = lane & 15, quad = lane >> 4;
  const int n = nt * 16 + l15, kb = ks * 32 + quad * 8;
  const float* row = src + ((size_t)s * 256 + n) * 256;
  union { bf16x8 v; unsigned short e[8]; } h;
#pragma unroll
  for (int j = 0; j < 8; ++j) h.e[j] = f2bf(row[kb + j]);
  out[(((size_t)s * 8 + ks) * 32 + ntOff + nt) * 64 + lane] = h.v;
}

// ---- fold vectors: kbv = Wk^T bq ; cbias = Wo bv + b_out ----
__global__ __launch_bounds__(256) void fold_vec2(const float* __restrict__ Win,
                                                 const float* __restrict__ bin,
                                                 const float* __restrict__ Wout,
                                                 const float* __restrict__ bout,
                                                 float* __restrict__ kbv,
                                                 float* __restrict__ cbias) {
  const int s = blockIdx.x, t = threadIdx.x;
  const float* bq = bin + s * 768;
  const float* bv = bin + s * 768 + 512;
  float a0 = 0.f, a1 = 0.f;
  for (int e = 0; e < 256; ++e) {
    a0 = fmaf(Win[((size_t)s * 768 + 256 + e) * 256 + t], bq[e], a0);
    a1 = fmaf(Wout[((size_t)s * 256 + t) * 256 + e], bv[e], a1);
  }
  kbv[s * 256 + t] = a0;
  cbias[s * 256 + t] = a1 + bout[s * 256 + t];
}

// ---- mvw[s][k] = sum_o wfo2[s][o] * Mv[s][o][k] ----
__global__ __launch_bounds__(256) void fold_mvw(const float* __restrict__ Mv,
                                                const float* __restrict__ Wfo,
                                                float* __restrict__ mvw) {
  const int s = blockIdx.x, k = threadIdx.x;
  float a = 0.f;
  for (int o = 0; o < 256; ++o)
    a = fmaf(Wfo[s * 512 + 256 + o], Mv[((size_t)s * 256 + o) * 256 + k], a);
  mvw[s * 256 + k] = a;
}

__global__ void fold_bias(const float* __restrict__ a, const float* __restrict__ b,
                          float* __restrict__ o, int n) {
  int i = blockIdx.x * 256 + threadIdx.x;
  if (i < n) o[i] = a[i] + b[i];
}

__global__ void build_decin(const float* __restrict__ x, const float* __restrict__ tgt,
                            float* __restrict__ dec_in) {
  int idx = blockIdx.x * 256 + threadIdx.x;
  if (idx >= LDEC * BATCH) return;
  int l = idx >> 10, b = idx & 1023;
  dec_in[idx] = (l == 0) ? x[(size_t)b * 96 * FDIM + 95 * FDIM]
                         : tgt[(size_t)b * LDEC + (l - 1)];
}

// =============== PHASE A: the recurrence (R14 geometry + pre-packed x) ===============
// Register model (R12-R15): granted arch VGPR = 65536/threads; MFMA accs add on
// top; waves/SIMD = floor(512/(arch+acc)). 512 thr -> 128+64=192 -> 2/SIMD (24%),
// the best measured geometry (R14: rec 2100 us). R14's residual 430 MB spill =
// the fp32->bf16 x-staging temps (~25 regs over the 128 cap). Fix: x is
// PRE-CONVERTED by pack_x; encoder A-frags now load directly as bf16 -> demand
// ~110 < 128 -> no spill. Biases/wfo in LDS (R14). Grid 256 = 1 round, XCD-pinned.
__global__ __launch_bounds__(512) void rec_phase(
    const unsigned short* __restrict__ xH, const unsigned short* __restrict__ xL,
    const bf16x8* __restrict__ WxH, const bf16x8* __restrict__ WxL,
    const bf16x8* __restrict__ WeH, const bf16x8* __restrict__ WeL,
    const bf16x8* __restrict__ WdH, const bf16x8* __restrict__ WdL,
    const float* __restrict__ be, const float* __restrict__ bd,
    const float* __restrict__ wihd, const float* __restrict__ Wfo,
    const float* __restrict__ decin,
    unsigned* __restrict__ hEnc,         // [t][s][b][e] packed hi|lo
    unsigned short* __restrict__ hDec,   // [l][s][b][e] bf16 hi
    float* __restrict__ hdPart)          // [l][s][b] = h_dec . wfo1 (fp32)
{
  __shared__ unsigned short hAhi[DBT * KA];   // 16.9 KB
  __shared__ unsigned short hAlo[DBT * KA];   // 16.9 KB
  __shared__ float beS[1024];                 // 4 KB
  __shared__ float bdS[1024];                 // 4 KB
  __shared__ float wdS[1024];                 // 4 KB
  __shared__ float wfoS[256];                 // 1 KB
  __shared__ float scrR[DBT * 8];             // 1 KB (hd partials)

  const int bid = blockIdx.x;
  const int s = bid & 7, b0 = (bid >> 3) * DBT;
  const int tid = threadIdx.x;
  const int w = tid >> 6, lane = tid & 63, l15 = lane & 15, quad = lane >> 4;

  for (int i = tid; i < DBT * KA; i += 512) { hAhi[i] = 0; hAlo[i] = 0; }
  for (int i = tid; i < 1024; i += 512) {
    beS[i] = be[s * 1024 + i];
    bdS[i] = bd[s * 1024 + i];
    wdS[i] = wihd[s * 1024 + i];
  }
  if (tid < 256) wfoS[tid] = Wfo[s * 512 + tid];

  float cst[2][2][4];
#pragma unroll
  for (int a = 0; a < 2; ++a)
#pragma unroll
    for (int b = 0; b < 2; ++b)
#pragma unroll
      for (int r = 0; r < 4; ++r) cst[a][b][r] = 0.f;

  const bf16x8* wxh = WxH + (size_t)s * 10 * 64 * 64;
  const bf16x8* wxl = WxL + (size_t)s * 10 * 64 * 64;
  const bf16x8* weh = WeH + (size_t)s * 8 * 64 * 64;
  const bf16x8* wel = WeL + (size_t)s * 8 * 64 * 64;
  const bf16x8* wdh = WdH + (size_t)s * 8 * 64 * 64;
  const bf16x8* wdl = WdL + (size_t)s * 8 * 64 * 64;

  __syncthreads();

  // ===================== encoder =====================
  for (int t = 0; t < TENC; ++t) {
    f32x4 acc[2][2][4];
#pragma unroll
    for (int mt = 0; mt < 2; ++mt)
#pragma unroll
      for (int st = 0; st < 2; ++st)
#pragma unroll
        for (int c = 0; c < 4; ++c) acc[mt][st][c] = (f32x4){0.f, 0.f, 0.f, 0.f};

    const size_t xoff = (size_t)(s * TENC + t) * FPAD;
    // x-part: 10 ksteps, A-frags loaded DIRECTLY as bf16 (pre-converted by pack_x)
    for (int ks = 0; ks < 10; ++ks) {
      bf16x8 axh[2], axl[2];
#pragma unroll
      for (int mt = 0; mt < 2; ++mt) {
        const size_t ro = (size_t)(b0 + 16 * mt + l15) * (96 * FPAD) + xoff
                        + ks * 32 + quad * 8;
        axh[mt] = *(const bf16x8*)&xH[ro];
        axl[mt] = *(const bf16x8*)&xL[ro];
      }
#pragma unroll
      for (int st = 0; st < 2; ++st)
#pragma unroll
        for (int c = 0; c < 4; ++c) {
          const int nt = c * 16 + 2 * w + st;
          const bf16x8 bh = wxh[(ks * 64 + nt) * 64 + lane];
          const bf16x8 bl = wxl[(ks * 64 + nt) * 64 + lane];
          MFMA(acc[0][st][c], axh[0], bh); MFMA(acc[0][st][c], axh[0], bl); MFMA(acc[0][st][c], axl[0], bh);
          MFMA(acc[1][st][c], axh[1], bh); MFMA(acc[1][st][c], axh[1], bl); MFMA(acc[1][st][c], axl[1], bh);
        }
    }
#pragma unroll 2
    for (int ks = 0; ks < 8; ++ks) {
      bf16x8 ah[2], al[2];
#pragma unroll
      for (int mt = 0; mt < 2; ++mt) {
        const int ao = (16 * mt + l15) * KA + ks * 32 + quad * 8;
        ah[mt] = *(const bf16x8*)&hAhi[ao];
        al[mt] = *(const bf16x8*)&hAlo[ao];
      }
#pragma unroll
      for (int st = 0; st < 2; ++st)
#pragma unroll
        for (int c = 0; c < 4; ++c) {
          const int nt = c * 16 + 2 * w + st;
          const bf16x8 bh = weh[(ks * 64 + nt) * 64 + lane];
          const bf16x8 bl = wel[(ks * 64 + nt) * 64 + lane];
          MFMA(acc[0][st][c], ah[0], bh); MFMA(acc[0][st][c], ah[0], bl); MFMA(acc[0][st][c], al[0], bh);
          MFMA(acc[1][st][c], ah[1], bh); MFMA(acc[1][st][c], ah[1], bl); MFMA(acc[1][st][c], al[1], bh);
        }
    }
    // pointwise LSTM -- gate biases from LDS table
    float hv[2][2][4];
#pragma unroll
    for (int st = 0; st < 2; ++st) {
      const int J0 = 32 * w + 16 * st + l15;
      const float g0 = beS[J0];
      const float g1 = beS[256 + J0];
      const float g2 = beS[512 + J0];
      const float g3 = beS[768 + J0];
#pragma unroll
      for (int mt = 0; mt < 2; ++mt)
#pragma unroll
        for (int reg = 0; reg < 4; ++reg) {
          const float gi = sigf(acc[mt][st][0][reg] + g0);
          const float gf = sigf(acc[mt][st][1][reg] + g1);
          const float gg = tanhf(acc[mt][st][2][reg] + g2);
          const float go = sigf(acc[mt][st][3][reg] + g3);
          const float cn = fmaf(gf, cst[mt][st][reg], gi * gg);
          cst[mt][st][reg] = cn;
          hv[mt][st][reg] = go * tanhf(cn);
        }
    }
    __syncthreads();
#pragma unroll
    for (int mt = 0; mt < 2; ++mt)
#pragma unroll
      for (int st = 0; st < 2; ++st)
#pragma unroll
        for (int reg = 0; reg < 4; ++reg) {
          const int R = 16 * mt + 4 * quad + reg;
          const int J = 32 * w + 16 * st + l15;
          const float v = hv[mt][st][reg];
          const unsigned short hi = f2bf(v);
          const unsigned short lo = f2bf(v - bflo(hi));
          hAhi[R * KA + J] = hi;
          hAlo[R * KA + J] = lo;
          __builtin_nontemporal_store((unsigned)hi | ((unsigned)lo << 16),
              &hEnc[((size_t)(t * S8 + s) * BATCH + b0 + R) * HDIM + J]);
        }
    __syncthreads();
  }

  // ===================== decoder (LSTM only + fp32 hd dot) =====================
  for (int l = 0; l < LDEC; ++l) {
    f32x4 acc[2][2][4];
#pragma unroll
    for (int mt = 0; mt < 2; ++mt)
#pragma unroll
      for (int st = 0; st < 2; ++st)
#pragma unroll
        for (int c = 0; c < 4; ++c) acc[mt][st][c] = (f32x4){0.f, 0.f, 0.f, 0.f};

#pragma unroll 2
    for (int ks = 0; ks < 8; ++ks) {
      bf16x8 ah[2], al[2];
#pragma unroll
      for (int mt = 0; mt < 2; ++mt) {
        const int ao = (16 * mt + l15) * KA + ks * 32 + quad * 8;
        ah[mt] = *(const bf16x8*)&hAhi[ao];
        al[mt] = *(const bf16x8*)&hAlo[ao];
      }
#pragma unroll
      for (int st = 0; st < 2; ++st)
#pragma unroll
        for (int c = 0; c < 4; ++c) {
          const int nt = c * 16 + 2 * w + st;
          const bf16x8 bh = wdh[(ks * 64 + nt) * 64 + lane];
          const bf16x8 bl = wdl[(ks * 64 + nt) * 64 + lane];
          MFMA(acc[0][st][c], ah[0], bh); MFMA(acc[0][st][c], ah[0], bl); MFMA(acc[0][st][c], al[0], bh);
          MFMA(acc[1][st][c], ah[1], bh); MFMA(acc[1][st][c], ah[1], bl); MFMA(acc[1][st][c], al[1], bh);
        }
    }
    // pointwise LSTM -- bd/wd from LDS tables
    float hv[2][2][4];
#pragma unroll
    for (int st = 0; st < 2; ++st) {
      const int J0 = 32 * w + 16 * st + l15;
      const float b0g = bdS[J0];
      const float b1g = bdS[256 + J0];
      const float b2g = bdS[512 + J0];
      const float b3g = bdS[768 + J0];
      const float w0g = wdS[J0];
      const float w1g = wdS[256 + J0];
      const float w2g = wdS[512 + J0];
      const float w3g = wdS[768 + J0];
#pragma unroll
      for (int mt = 0; mt < 2; ++mt)
#pragma unroll
        for (int reg = 0; reg < 4; ++reg) {
          const int R = 16 * mt + 4 * quad + reg;
          const float it = decin[(size_t)l * BATCH + b0 + R];
          const float gi = sigf(fmaf(it, w0g, acc[mt][st][0][reg] + b0g));
          const float gf = sigf(fmaf(it, w1g, acc[mt][st][1][reg] + b1g));
          const float gg = tanhf(fmaf(it, w2g, acc[mt][st][2][reg] + b2g));
          const float go = sigf(fmaf(it, w3g, acc[mt][st][3][reg] + b3g));
          const float cn = fmaf(gf, cst[mt][st][reg], gi * gg);
          cst[mt][st][reg] = cn;
          hv[mt][st][reg] = go * tanhf(cn);
        }
    }
    __syncthreads();
#pragma unroll
    for (int mt = 0; mt < 2; ++mt)
#pragma unroll
      for (int st = 0; st < 2; ++st)
#pragma unroll
        for (int reg = 0; reg < 4; ++reg) {
          const int R = 16 * mt + 4 * quad + reg;
          const int J = 32 * w + 16 * st + l15;
          const float v = hv[mt][st][reg];
          const unsigned short hi = f2bf(v);
          hAhi[R * KA + J] = hi;
          hAlo[R * KA + J] = f2bf(v - bflo(hi));
          __builtin_nontemporal_store(hi,
              &hDec[((size_t)(l * S8 + s) * BATCH + b0 + R) * HDIM + J]);
        }
    // hd = h . wfo1 in fp32 from registers
    {
      float part[8];
#pragma unroll
      for (int mt = 0; mt < 2; ++mt)
#pragma unroll
        for (int reg = 0; reg < 4; ++reg) {
          const int J0 = 32 * w + l15;
          part[mt * 4 + reg] = hv[mt][0][reg] * wfoS[J0] + hv[mt][1][reg] * wfoS[J0 + 16];
        }
#pragma unroll
      for (int i = 0; i < 8; ++i) {
        float v = part[i];
        v += __shfl_xor(v, 1, 16);
        v += __shfl_xor(v, 2, 16);
        v += __shfl_xor(v, 4, 16);
        v += __shfl_xor(v, 8, 16);
        part[i] = v;
      }
      if (l15 == 0) {
#pragma unroll
        for (int mt = 0; mt < 2; ++mt)
#pragma unroll
          for (int reg = 0; reg < 4; ++reg)
            scrR[(16 * mt + 4 * quad + reg) * 8 + w] = part[mt * 4 + reg];
      }
    }
    __syncthreads();
    if (tid < DBT) {
      float a = 0.f;
#pragma unroll
      for (int p = 0; p < 8; ++p) a += scrR[tid * 8 + p];
      hdPart[((size_t)l * S8 + s) * BATCH + b0 + tid] = a;
    }
    // no extra barrier: scrR's next write is after next iter's first sync
  }
}

// =============== PHASE B: attention + output, fully parallel ===============
__global__ __launch_bounds__(256) void attn_phase(
    const unsigned* __restrict__ hEnc, const unsigned short* __restrict__ hDec,
    const bf16x8* __restrict__ AMvF,
    const float* __restrict__ kbv, const float* __restrict__ cbias,
    const float* __restrict__ mvw,
    const float* __restrict__ Wfo, const float* __restrict__ bfo,
    const float* __restrict__ hdPart,
    float* __restrict__ douts)
{
  __shared__ unsigned short kpL[TENC][16][KA];  // 101.4 KB
  __shared__ float scr[16 * TENC * 17];         // 13.1 KB
  __shared__ float sc[16][TENC];
  __shared__ float kbs[TENC][16];
  __shared__ float vw[TENC][16];

  const int s = blockIdx.y, b0 = blockIdx.x * 16;
  const int tid = threadIdx.x;
  const int w = tid >> 6, lane = tid & 63, l15 = lane & 15, quad = lane >> 4;

  const bf16x8* amv = AMvF + (size_t)s * 8 * 32 * 64;
  const float* kvv = kbv + s * 256;
  const float* mvv = mvw + s * 256;
  const float* cbs = cbias + s * 256;
  const float* wfo = Wfo + s * 512;
  const float bfos = bfo[s];

  float cw = 0.f;
  for (int e = 0; e < 256; ++e) cw = fmaf(cbs[e], wfo[256 + e], cw);

  // --- kp[t] = P . h_enc[t] via MFMA (hi+lo A); rows via l15, nt = 4w+c ---
  for (int t = 0; t < TENC; ++t) {
    f32x4 acc[4];
#pragma unroll
    for (int c = 0; c < 4; ++c) acc[c] = (f32x4){0.f, 0.f, 0.f, 0.f};
    for (int ks = 0; ks < 8; ++ks) {
      const unsigned* hp = hEnc + ((size_t)(t * S8 + s) * BATCH + b0 + l15) * HDIM
                         + ks * 32 + quad * 8;
      union { bf16x8 v; unsigned short e[8]; } uh, ul;
#pragma unroll
      for (int j = 0; j < 8; ++j) {
        const unsigned u = hp[j];
        uh.e[j] = (unsigned short)u;
        ul.e[j] = (unsigned short)(u >> 16);
      }
#pragma unroll
      for (int c = 0; c < 4; ++c) {
        const int nt = w * 4 + c;
        const bf16x8 b = amv[(ks * 32 + nt) * 64 + lane];
        MFMA(acc[c], uh.v, b); MFMA(acc[c], ul.v, b);
      }
    }
#pragma unroll
    for (int c = 0; c < 4; ++c)
#pragma unroll
      for (int reg = 0; reg < 4; ++reg)
        kpL[t][4 * quad + reg][(w * 4 + c) * 16 + l15] = f2bf(acc[c][reg]);
  }
  // --- kbs / vw folds from h_enc (hi+lo floats) ---
  for (int t = 0; t < TENC; ++t) {
    const int row = tid >> 4, p = tid & 15;
    const unsigned* hp = hEnc + ((size_t)(t * S8 + s) * BATCH + b0 + row) * HDIM + p * 16;
    float a = 0.f, b = 0.f;
#pragma unroll
    for (int k = 0; k < 16; ++k) {
      const unsigned u = hp[k];
      const float h = bflo(u) + bfhi(u);
      a = fmaf(kvv[p * 16 + k], h, a);
      b = fmaf(mvv[p * 16 + k], h, b);
    }
    scr[row * 34 + p] = a;
    scr[row * 34 + 17 + p] = b;
    __syncthreads();
    if (tid < 16) {
      float sa = 0.f, sb = 0.f;
#pragma unroll
      for (int p2 = 0; p2 < 16; ++p2) { sa += scr[tid * 34 + p2]; sb += scr[tid * 34 + 17 + p2]; }
      kbs[t][tid] = sa;
      vw[t][tid] = sb;
    }
    __syncthreads();
  }

  // --- per-l scores/softmax/out ---
  for (int l = 0; l < LDEC; ++l) {
    const int row = tid & 15, pp = tid >> 4;
    float hh[16];
    {
      const unsigned short* hp = hDec + ((size_t)(l * S8 + s) * BATCH + b0 + row) * HDIM + pp * 16;
      const uint4 q0 = *(const uint4*)hp;
      const uint4 q1 = *(const uint4*)(hp + 8);
      UNPS(hh, 0, q0);
      UNPS(hh, 8, q1);
    }
#pragma unroll 2
    for (int t = 0; t < TENC; ++t) {
      const uint4 q0 = *(const uint4*)&kpL[t][row][pp * 16];
      const uint4 q1 = *(const uint4*)&kpL[t][row][pp * 16 + 8];
      float a = 0.f;
      { const float* hp8 = &hh[0]; DOT8(a, q0, hp8); }
      { const float* hp8 = &hh[8]; DOT8(a, q1, hp8); }
      scr[(row * TENC + t) * 17 + pp] = a;
    }
    __syncthreads();
    if (tid < 192) {
      const int r2 = tid & 15, t2 = tid >> 4;
      float a = kbs[t2][r2];
#pragma unroll
      for (int p2 = 0; p2 < 16; ++p2) a += scr[(r2 * TENC + t2) * 17 + p2];
      sc[r2][t2] = a * SCALE_ATTN;
    }
    __syncthreads();
    if (tid < 16) {
      float m = sc[tid][0];
#pragma unroll
      for (int t2 = 1; t2 < TENC; ++t2) m = fmaxf(m, sc[tid][t2]);
      float e[TENC], sum = 0.f;
#pragma unroll
      for (int t2 = 0; t2 < TENC; ++t2) { e[t2] = expf(sc[tid][t2] - m); sum += e[t2]; }
      const float inv = 1.0f / sum;
      float av = 0.f;
#pragma unroll
      for (int t2 = 0; t2 < TENC; ++t2) av = fmaf(e[t2] * inv, vw[t2][tid], av);
      const float hd = hdPart[((size_t)l * S8 + s) * BATCH + b0 + tid];
      douts[((size_t)l * S8 + s) * BATCH + b0 + tid] = hd + av + cw + bfos;
    }
    __syncthreads();
  }
}

// ---------------- final fc over streams ----------------
__global__ void final_fc(const float* __restrict__ douts, const float* __restrict__ Wfc,
                         const float* __restrict__ bfc, float* __restrict__ out) {
  int idx = blockIdx.x * 256 + threadIdx.x;
  if (idx >= BATCH * LDEC) return;
  int b = idx / LDEC, l = idx - b * LDEC;
  float a = bfc[0];
#pragma unroll
  for (int s = 0; s < S8; ++s)
    a = fmaf(douts[((size_t)l * S8 + s) * BATCH + b], Wfc[s], a);
  out[idx] = a;
}

extern "C" void kernel_launch(void* const* d_in, const int* in_sizes, int n_in,
                              void* d_out, int out_size, void* d_ws, size_t ws_size,
                              hipStream_t stream) {
  const float* x          = (const float*)d_in[0];
  const float* tgt        = (const float*)d_in[1];
  const float* W_ih_e     = (const float*)d_in[2];
  const float* W_hh_e     = (const float*)d_in[3];
  const float* b_ih_e     = (const float*)d_in[4];
  const float* b_hh_e     = (const float*)d_in[5];
  const float* W_ih_d     = (const float*)d_in[6];
  const float* W_hh_d     = (const float*)d_in[7];
  const float* b_ih_d     = (const float*)d_in[8];
  const float* b_hh_d     = (const float*)d_in[9];
  const float* W_in_attn  = (const float*)d_in[10];
  const float* b_in_attn  = (const float*)d_in[11];
  const float* W_out_attn = (const float*)d_in[12];
  const float* b_out_attn = (const float*)d_in[13];
  const float* W_fcout    = (const float*)d_in[14];
  const float* b_fcout    = (const float*)d_in[15];
  const float* W_fc       = (const float*)d_in[16];
  const float* b_fc       = (const float*)d_in[17];

  char* wsb = (char*)d_ws;
  size_t off = 0;
  auto alloc = [&](size_t bytes) {
    void* p = wsb + off; off += (bytes + 255) & ~(size_t)255; return p;
  };
  float*  douts = (float*)alloc((size_t)LDEC * S8 * BATCH * 4);
  float*  decin = (float*)alloc((size_t)LDEC * BATCH * 4);
  float*  hdPart= (float*)alloc((size_t)LDEC * S8 * BATCH * 4);
  float*  Pmat  = (float*)alloc((size_t)S8 * 256 * 256 * 4);
  float*  Mvmat = (float*)alloc((size_t)S8 * 256 * 256 * 4);
  float*  WoT   = (float*)alloc((size_t)S8 * 256 * 256 * 4);
  bf16x8* WxH   = (bf16x8*)alloc((size_t)S8 * 10 * 64 * 64 * 16);
  bf16x8* WxL   = (bf16x8*)alloc((size_t)S8 * 10 * 64 * 64 * 16);
  bf16x8* WeH   = (bf16x8*)alloc((size_t)S8 * 8 * 64 * 64 * 16);
  bf16x8* WeL   = (bf16x8*)alloc((size_t)S8 * 8 * 64 * 64 * 16);
  bf16x8* WdH   = (bf16x8*)alloc((size_t)S8 * 8 * 64 * 64 * 16);
  bf16x8* WdL   = (bf16x8*)alloc((size_t)S8 * 8 * 64 * 64 * 16);
  bf16x8* AMvF  = (bf16x8*)alloc((size_t)S8 * 8 * 32 * 64 * 16);
  float*  kbv   = (float*)alloc((size_t)S8 * 256 * 4);
  float*  cbias = (float*)alloc((size_t)S8 * 256 * 4);
  float*  mvw   = (float*)alloc((size_t)S8 * 256 * 4);
  float*  beF   = (float*)alloc((size_t)S8 * 1024 * 4);
  float*  bdF   = (float*)alloc((size_t)S8 * 1024 * 4);
  unsigned* hEnc = (unsigned*)alloc((size_t)TENC * S8 * BATCH * HDIM * 4);             // 100.7 MB
  unsigned short* hDec = (unsigned short*)alloc((size_t)LDEC * S8 * BATCH * HDIM * 2); // 201.3 MB
  unsigned short* xHb = (unsigned short*)alloc((size_t)BATCH * 96 * FPAD * 2);         // 62.9 MB
  unsigned short* xLb = (unsigned short*)alloc((size_t)BATCH * 96 * FPAD * 2);         // 62.9 MB
  if (off > ws_size) {
    fprintf(stderr, "kernel_launch: ws too small: need %zu bytes, have %zu\n", off, ws_size);
    return;
  }

  // ---- one-time weight/input preparation ----
  transpose_k<<<dim3(8, 8, S8), 256, 0, stream>>>(W_out_attn, WoT, 256, 256);
  fold_gemm<<<dim3(8, S8), 256, 0, stream>>>(W_in_attn, (size_t)768 * 256,
                                             W_in_attn + 256 * 256, (size_t)768 * 256,
                                             Pmat, (size_t)256 * 256);
  fold_gemm<<<dim3(8, S8), 256, 0, stream>>>(WoT, (size_t)256 * 256,
                                             W_in_attn + 2 * 256 * 256, (size_t)768 * 256,
                                             Mvmat, (size_t)256 * 256);
  pack_x<<<(int)(((size_t)BATCH * 96 * FPAD + 255) / 256), 256, 0, stream>>>(x, xHb, xLb);
  pack_hl<<<dim3(64, 10, S8), 64, 0, stream>>>(W_ih_e, FDIM, 10, WxH, WxL);
  pack_hl<<<dim3(64, 8, S8), 64, 0, stream>>>(W_hh_e, 256, 8, WeH, WeL);
  pack_hl<<<dim3(64, 8, S8), 64, 0, stream>>>(W_hh_d, 256, 8, WdH, WdL);
  pack_s<<<dim3(16, 8, S8), 64, 0, stream>>>(Pmat, 0, AMvF);
  fold_vec2<<<S8, 256, 0, stream>>>(W_in_attn, b_in_attn, W_out_attn, b_out_attn, kbv, cbias);
  fold_mvw<<<S8, 256, 0, stream>>>(Mvmat, W_fcout, mvw);
  fold_bias<<<(S8 * 1024 + 255) / 256, 256, 0, stream>>>(b_ih_e, b_hh_e, beF, S8 * 1024);
  fold_bias<<<(S8 * 1024 + 255) / 256, 256, 0, stream>>>(b_ih_d, b_hh_d, bdF, S8 * 1024);
  build_decin<<<(LDEC * BATCH + 255) / 256, 256, 0, stream>>>(x, tgt, decin);

  // Phase A: the recurrence only (R14 geometry + pre-packed x -> no spill)
  rec_phase<<<256, 512, 0, stream>>>(
      xHb, xLb, WxH, WxL, WeH, WeL, WdH, WdL, beF, bdF, W_ih_d, W_fcout, decin,
      hEnc, hDec, hdPart);

  // Phase B: attention + outputs (fully parallel over l and batch)
  attn_phase<<<dim3(64, S8), 256, 0, stream>>>(
      hEnc, hDec, AMvF, kbv, cbias, mvw, W_fcout, b_fcout, hdPart, douts);

  final_fc<<<(BATCH * LDEC + 255) / 256, 256, 0, stream>>>(douts, W_fc, b_fc, (float*)d_out);
}

// Round 17
// 2772.159 us; speedup vs baseline: 1.6523x; 1.2474x over previous
//
#include <hip/hip_runtime.h>
#include <cstdio>
#include <cstdint>

#define S8     8
#define TENC   12
#define HDIM   256
#define FDIM   316
#define BATCH  1024
#define LDEC   48
#define DBT    32           // batch rows per block in rec_phase; grid 256 = 1 block/CU
#define KA     264          // hA row stride in shorts (16B-aligned rows)
#define SCALE_ATTN 0.0625f  // 1/sqrt(256)

typedef short bf16x8 __attribute__((ext_vector_type(8)));
typedef float f32x4  __attribute__((ext_vector_type(4)));

__device__ __forceinline__ float sigf(float x) { return 1.0f / (1.0f + expf(-x)); }

__device__ __forceinline__ unsigned short f2bf(float f) {
  unsigned u = __builtin_bit_cast(unsigned, f);
  unsigned r = (u + 0x7fffu + ((u >> 16) & 1u)) >> 16;   // RNE
  return (unsigned short)r;
}
__device__ __forceinline__ float bflo(unsigned u) {
  return __builtin_bit_cast(float, u << 16);
}
__device__ __forceinline__ float bfhi(unsigned u) {
  return __builtin_bit_cast(float, u & 0xffff0000u);
}

#define MFMA(acc, a, b) acc = __builtin_amdgcn_mfma_f32_16x16x32_bf16(a, b, acc, 0, 0, 0)

// DOT8: q = 4 u32 holding 8 bf16 (lo/hi pairs), hp = 8 floats
#define DOT8(a, q, hp) \
  a = fmaf(bflo(q.x), hp[0], a); a = fmaf(bfhi(q.x), hp[1], a); \
  a = fmaf(bflo(q.y), hp[2], a); a = fmaf(bfhi(q.y), hp[3], a); \
  a = fmaf(bflo(q.z), hp[4], a); a = fmaf(bfhi(q.z), hp[5], a); \
  a = fmaf(bflo(q.w), hp[6], a); a = fmaf(bfhi(q.w), hp[7], a);

// UNPS: 4 u32 (= 8 ushorts of a bf16 array) -> 8 floats
#define UNPS(dst, off, q) \
  dst[off+0] = bflo(q.x); dst[off+1] = bfhi(q.x); \
  dst[off+2] = bflo(q.y); dst[off+3] = bfhi(q.y); \
  dst[off+4] = bflo(q.z); dst[off+5] = bfhi(q.z); \
  dst[off+6] = bflo(q.w); dst[off+7] = bfhi(q.w);

// ---------------- transpose: in [S][R][C] -> out [S][C][R] ----------------
__global__ __launch_bounds__(256) void transpose_k(const float* __restrict__ in,
                                                   float* __restrict__ out,
                                                   int R, int C) {
  __shared__ float tile[32][33];
  const int s = blockIdx.z;
  const size_t base = (size_t)s * R * C;
  const int r0 = blockIdx.y * 32, c0 = blockIdx.x * 32;
  const int tx = threadIdx.x & 31, ty = threadIdx.x >> 5;
  for (int i = ty; i < 32; i += 8) {
    int r = r0 + i, c = c0 + tx;
    if (r < R && c < C) tile[i][tx] = in[base + (size_t)r * C + c];
  }
  __syncthreads();
  for (int i = ty; i < 32; i += 8) {
    int c = c0 + i, r = r0 + tx;
    if (c < C && r < R) out[base + (size_t)c * R + r] = tile[tx][i];
  }
}

// ---- fold GEMM: out[s][r][col] = sum_e A[s][e][r] * B[s][e][col], 256x256, K=256 ----
__global__ __launch_bounds__(256) void fold_gemm(const float* __restrict__ A, size_t sA,
                                                 const float* __restrict__ Bm, size_t sB,
                                                 float* __restrict__ out, size_t sO) {
  const int s = blockIdx.y, r0 = blockIdx.x * 32, col = threadIdx.x;
  A += (size_t)s * sA; Bm += (size_t)s * sB; out += (size_t)s * sO;
  float acc[32] = {};
  for (int e = 0; e < HDIM; ++e) {
    const float bvv = Bm[(size_t)e * HDIM + col];
#pragma unroll
    for (int r = 0; r < 32; ++r) acc[r] = fmaf(A[(size_t)e * HDIM + r0 + r], bvv, acc[r]);
  }
  for (int r = 0; r < 32; ++r) out[(size_t)(r0 + r) * HDIM + col] = acc[r];
}

// ---- pack gate weights [S][1024][Ksrc] into B-fragment layout, hi+lo bf16 ----
__global__ __launch_bounds__(64) void pack_hl(const float* __restrict__ src, int Ksrc, int ksT,
                                              bf16x8* __restrict__ outhi,
                                              bf16x8* __restrict__ outlo) {
  const int s = blockIdx.z, ks = blockIdx.y, nt = blockIdx.x;
  const int lane = threadIdx.x, l15 = lane & 15, quad = lane >> 4;
  const int n = nt * 16 + l15, kb = ks * 32 + quad * 8;
  const float* row = src + ((size_t)s * 1024 + n) * Ksrc;
  union { bf16x8 v; unsigned short e[8]; } h, l;
#pragma unroll
  for (int j = 0; j < 8; ++j) {
    const int k = kb + j;
    const float v = (k < Ksrc) ? row[k] : 0.f;
    const unsigned short hi = f2bf(v);
    h.e[j] = hi;
    l.e[j] = f2bf(v - bflo(hi));
  }
  const size_t idx = (((size_t)s * ksT + ks) * 64 + nt) * 64 + lane;
  outhi[idx] = h.v;
  outlo[idx] = l.v;
}

// ---- pack attention fold matrix P [S][256][256] into B-frag (single bf16), nt 0..15 ----
__global__ __launch_bounds__(64) void pack_s(const float* __restrict__ src, int ntOff,
                                             bf16x8* __restrict__ out) {
  const int s = blockIdx.z, ks = blockIdx.y, nt = blockIdx.x;
  const int lane = threadIdx.x, l15 = lane & 15, quad = lane >> 4;
  const int n = nt * 16 + l15, kb = ks * 32 + quad * 8;
  const float* row = src + ((size_t)s * 256 + n) * 256;
  union { bf16x8 v; unsigned short e[8]; } h;
#pragma unroll
  for (int j = 0; j < 8; ++j) h.e[j] = f2bf(row[kb + j]);
  out[(((size_t)s * 8 + ks) * 32 + ntOff + nt) * 64 + lane] = h.v;
}

// ---- fold vectors: kbv = Wk^T bq ; cbias = Wo bv + b_out ----
__global__ __launch_bounds__(256) void fold_vec2(const float* __restrict__ Win,
                                                 const float* __restrict__ bin,
                                                 const float* __restrict__ Wout,
                                                 const float* __restrict__ bout,
                                                 float* __restrict__ kbv,
                                                 float* __restrict__ cbias) {
  const int s = blockIdx.x, t = threadIdx.x;
  const float* bq = bin + s * 768;
  const float* bv = bin + s * 768 + 512;
  float a0 = 0.f, a1 = 0.f;
  for (int e = 0; e < 256; ++e) {
    a0 = fmaf(Win[((size_t)s * 768 + 256 + e) * 256 + t], bq[e], a0);
    a1 = fmaf(Wout[((size_t)s * 256 + t) * 256 + e], bv[e], a1);
  }
  kbv[s * 256 + t] = a0;
  cbias[s * 256 + t] = a1 + bout[s * 256 + t];
}

// ---- mvw[s][k] = sum_o wfo2[s][o] * Mv[s][o][k] ----
__global__ __launch_bounds__(256) void fold_mvw(const float* __restrict__ Mv,
                                                const float* __restrict__ Wfo,
                                                float* __restrict__ mvw) {
  const int s = blockIdx.x, k = threadIdx.x;
  float a = 0.f;
  for (int o = 0; o < 256; ++o)
    a = fmaf(Wfo[s * 512 + 256 + o], Mv[((size_t)s * 256 + o) * 256 + k], a);
  mvw[s * 256 + k] = a;
}

__global__ void fold_bias(const float* __restrict__ a, const float* __restrict__ b,
                          float* __restrict__ o, int n) {
  int i = blockIdx.x * 256 + threadIdx.x;
  if (i < n) o[i] = a[i] + b[i];
}

__global__ void build_decin(const float* __restrict__ x, const float* __restrict__ tgt,
                            float* __restrict__ dec_in) {
  int idx = blockIdx.x * 256 + threadIdx.x;
  if (idx >= LDEC * BATCH) return;
  int l = idx >> 10, b = idx & 1023;
  dec_in[idx] = (l == 0) ? x[(size_t)b * 96 * FDIM + 95 * FDIM]
                         : tgt[(size_t)b * LDEC + (l - 1)];
}

// =============== PHASE A: the recurrence, and ONLY the recurrence ===============
// R14 configuration — verified best (rec 2100 us, total 2710 us).
// Phase split: scores/softmax/ctx/out are OFF the recurrent critical path.
// 512 thr, DBT=32, grid 256 = 1 block/CU, ONE dispatch round, XCD = bid%8 pins
// one stream's weights per XCD L2. Biases/wfo in LDS. h_enc streamed as packed
// hi|lo u32; h_dec as bf16-hi; hd = h.wfo1 computed in fp32 from registers.
// NOTE (R15/R16): do NOT perturb this kernel's register schedule — both the
// 1024-thread variant and the pre-packed-x variant regressed (allocator
// spill choices at the 128-reg point are chaotic; this codegen is a verified
// local optimum).
__global__ __launch_bounds__(512) void rec_phase(
    const float* __restrict__ x,
    const bf16x8* __restrict__ WxH, const bf16x8* __restrict__ WxL,
    const bf16x8* __restrict__ WeH, const bf16x8* __restrict__ WeL,
    const bf16x8* __restrict__ WdH, const bf16x8* __restrict__ WdL,
    const float* __restrict__ be, const float* __restrict__ bd,
    const float* __restrict__ wihd, const float* __restrict__ Wfo,
    const float* __restrict__ decin,
    unsigned* __restrict__ hEnc,         // [t][s][b][e] packed hi|lo
    unsigned short* __restrict__ hDec,   // [l][s][b][e] bf16 hi
    float* __restrict__ hdPart)          // [l][s][b] = h_dec . wfo1 (fp32)
{
  __shared__ unsigned short hAhi[DBT * KA];   // 16.9 KB
  __shared__ unsigned short hAlo[DBT * KA];   // 16.9 KB
  __shared__ float beS[1024];                 // 4 KB
  __shared__ float bdS[1024];                 // 4 KB
  __shared__ float wdS[1024];                 // 4 KB
  __shared__ float wfoS[256];                 // 1 KB
  __shared__ float scrR[DBT * 8];             // 1 KB (hd partials)

  const int bid = blockIdx.x;
  const int s = bid & 7, b0 = (bid >> 3) * DBT;
  const int tid = threadIdx.x;
  const int w = tid >> 6, lane = tid & 63, l15 = lane & 15, quad = lane >> 4;

  for (int i = tid; i < DBT * KA; i += 512) { hAhi[i] = 0; hAlo[i] = 0; }
  for (int i = tid; i < 1024; i += 512) {
    beS[i] = be[s * 1024 + i];
    bdS[i] = bd[s * 1024 + i];
    wdS[i] = wihd[s * 1024 + i];
  }
  if (tid < 256) wfoS[tid] = Wfo[s * 512 + tid];

  float cst[2][2][4];
#pragma unroll
  for (int a = 0; a < 2; ++a)
#pragma unroll
    for (int b = 0; b < 2; ++b)
#pragma unroll
      for (int r = 0; r < 4; ++r) cst[a][b][r] = 0.f;

  const bf16x8* wxh = WxH + (size_t)s * 10 * 64 * 64;
  const bf16x8* wxl = WxL + (size_t)s * 10 * 64 * 64;
  const bf16x8* weh = WeH + (size_t)s * 8 * 64 * 64;
  const bf16x8* wel = WeL + (size_t)s * 8 * 64 * 64;
  const bf16x8* wdh = WdH + (size_t)s * 8 * 64 * 64;
  const bf16x8* wdl = WdL + (size_t)s * 8 * 64 * 64;

  __syncthreads();

  // ===================== encoder =====================
  for (int t = 0; t < TENC; ++t) {
    f32x4 acc[2][2][4];
#pragma unroll
    for (int mt = 0; mt < 2; ++mt)
#pragma unroll
      for (int st = 0; st < 2; ++st)
#pragma unroll
        for (int c = 0; c < 4; ++c) acc[mt][st][c] = (f32x4){0.f, 0.f, 0.f, 0.f};

    const size_t xoff = (size_t)(s * TENC + t) * FDIM;
    for (int ks = 0; ks < 10; ++ks) {
      bf16x8 axh[2], axl[2];
#pragma unroll
      for (int mt = 0; mt < 2; ++mt) {
        const f32x4* xr = (const f32x4*)(x + (size_t)(b0 + 16 * mt + l15) * (96 * FDIM)
                                         + xoff + ks * 32 + quad * 8);
        const f32x4 v0 = __builtin_nontemporal_load(xr);
        f32x4 v1;
        if (ks == 9 && quad == 3) v1 = (f32x4){0.f, 0.f, 0.f, 0.f};
        else v1 = __builtin_nontemporal_load(xr + 1);
        float vv[8];
#pragma unroll
        for (int j = 0; j < 4; ++j) { vv[j] = v0[j]; vv[4 + j] = v1[j]; }
        union { bf16x8 v; unsigned short e[8]; } uh, ul;
#pragma unroll
        for (int j = 0; j < 8; ++j) {
          const unsigned short hi = f2bf(vv[j]);
          uh.e[j] = hi;
          ul.e[j] = f2bf(vv[j] - bflo(hi));
        }
        axh[mt] = uh.v; axl[mt] = ul.v;
      }
#pragma unroll
      for (int st = 0; st < 2; ++st)
#pragma unroll
        for (int c = 0; c < 4; ++c) {
          const int nt = c * 16 + 2 * w + st;
          const bf16x8 bh = wxh[(ks * 64 + nt) * 64 + lane];
          const bf16x8 bl = wxl[(ks * 64 + nt) * 64 + lane];
          MFMA(acc[0][st][c], axh[0], bh); MFMA(acc[0][st][c], axh[0], bl); MFMA(acc[0][st][c], axl[0], bh);
          MFMA(acc[1][st][c], axh[1], bh); MFMA(acc[1][st][c], axh[1], bl); MFMA(acc[1][st][c], axl[1], bh);
        }
    }
#pragma unroll 2
    for (int ks = 0; ks < 8; ++ks) {
      bf16x8 ah[2], al[2];
#pragma unroll
      for (int mt = 0; mt < 2; ++mt) {
        const int ao = (16 * mt + l15) * KA + ks * 32 + quad * 8;
        ah[mt] = *(const bf16x8*)&hAhi[ao];
        al[mt] = *(const bf16x8*)&hAlo[ao];
      }
#pragma unroll
      for (int st = 0; st < 2; ++st)
#pragma unroll
        for (int c = 0; c < 4; ++c) {
          const int nt = c * 16 + 2 * w + st;
          const bf16x8 bh = weh[(ks * 64 + nt) * 64 + lane];
          const bf16x8 bl = wel[(ks * 64 + nt) * 64 + lane];
          MFMA(acc[0][st][c], ah[0], bh); MFMA(acc[0][st][c], ah[0], bl); MFMA(acc[0][st][c], al[0], bh);
          MFMA(acc[1][st][c], ah[1], bh); MFMA(acc[1][st][c], ah[1], bl); MFMA(acc[1][st][c], al[1], bh);
        }
    }
    // pointwise LSTM -- gate biases from LDS table
    float hv[2][2][4];
#pragma unroll
    for (int st = 0; st < 2; ++st) {
      const int J0 = 32 * w + 16 * st + l15;
      const float g0 = beS[J0];
      const float g1 = beS[256 + J0];
      const float g2 = beS[512 + J0];
      const float g3 = beS[768 + J0];
#pragma unroll
      for (int mt = 0; mt < 2; ++mt)
#pragma unroll
        for (int reg = 0; reg < 4; ++reg) {
          const float gi = sigf(acc[mt][st][0][reg] + g0);
          const float gf = sigf(acc[mt][st][1][reg] + g1);
          const float gg = tanhf(acc[mt][st][2][reg] + g2);
          const float go = sigf(acc[mt][st][3][reg] + g3);
          const float cn = fmaf(gf, cst[mt][st][reg], gi * gg);
          cst[mt][st][reg] = cn;
          hv[mt][st][reg] = go * tanhf(cn);
        }
    }
    __syncthreads();
#pragma unroll
    for (int mt = 0; mt < 2; ++mt)
#pragma unroll
      for (int st = 0; st < 2; ++st)
#pragma unroll
        for (int reg = 0; reg < 4; ++reg) {
          const int R = 16 * mt + 4 * quad + reg;
          const int J = 32 * w + 16 * st + l15;
          const float v = hv[mt][st][reg];
          const unsigned short hi = f2bf(v);
          const unsigned short lo = f2bf(v - bflo(hi));
          hAhi[R * KA + J] = hi;
          hAlo[R * KA + J] = lo;
          __builtin_nontemporal_store((unsigned)hi | ((unsigned)lo << 16),
              &hEnc[((size_t)(t * S8 + s) * BATCH + b0 + R) * HDIM + J]);
        }
    __syncthreads();
  }

  // ===================== decoder (LSTM only + fp32 hd dot) =====================
  for (int l = 0; l < LDEC; ++l) {
    f32x4 acc[2][2][4];
#pragma unroll
    for (int mt = 0; mt < 2; ++mt)
#pragma unroll
      for (int st = 0; st < 2; ++st)
#pragma unroll
        for (int c = 0; c < 4; ++c) acc[mt][st][c] = (f32x4){0.f, 0.f, 0.f, 0.f};

#pragma unroll 2
    for (int ks = 0; ks < 8; ++ks) {
      bf16x8 ah[2], al[2];
#pragma unroll
      for (int mt = 0; mt < 2; ++mt) {
        const int ao = (16 * mt + l15) * KA + ks * 32 + quad * 8;
        ah[mt] = *(const bf16x8*)&hAhi[ao];
        al[mt] = *(const bf16x8*)&hAlo[ao];
      }
#pragma unroll
      for (int st = 0; st < 2; ++st)
#pragma unroll
        for (int c = 0; c < 4; ++c) {
          const int nt = c * 16 + 2 * w + st;
          const bf16x8 bh = wdh[(ks * 64 + nt) * 64 + lane];
          const bf16x8 bl = wdl[(ks * 64 + nt) * 64 + lane];
          MFMA(acc[0][st][c], ah[0], bh); MFMA(acc[0][st][c], ah[0], bl); MFMA(acc[0][st][c], al[0], bh);
          MFMA(acc[1][st][c], ah[1], bh); MFMA(acc[1][st][c], ah[1], bl); MFMA(acc[1][st][c], al[1], bh);
        }
    }
    // pointwise LSTM -- bd/wd from LDS tables
    float hv[2][2][4];
#pragma unroll
    for (int st = 0; st < 2; ++st) {
      const int J0 = 32 * w + 16 * st + l15;
      const float b0g = bdS[J0];
      const float b1g = bdS[256 + J0];
      const float b2g = bdS[512 + J0];
      const float b3g = bdS[768 + J0];
      const float w0g = wdS[J0];
      const float w1g = wdS[256 + J0];
      const float w2g = wdS[512 + J0];
      const float w3g = wdS[768 + J0];
#pragma unroll
      for (int mt = 0; mt < 2; ++mt)
#pragma unroll
        for (int reg = 0; reg < 4; ++reg) {
          const int R = 16 * mt + 4 * quad + reg;
          const float it = decin[(size_t)l * BATCH + b0 + R];
          const float gi = sigf(fmaf(it, w0g, acc[mt][st][0][reg] + b0g));
          const float gf = sigf(fmaf(it, w1g, acc[mt][st][1][reg] + b1g));
          const float gg = tanhf(fmaf(it, w2g, acc[mt][st][2][reg] + b2g));
          const float go = sigf(fmaf(it, w3g, acc[mt][st][3][reg] + b3g));
          const float cn = fmaf(gf, cst[mt][st][reg], gi * gg);
          cst[mt][st][reg] = cn;
          hv[mt][st][reg] = go * tanhf(cn);
        }
    }
    __syncthreads();
#pragma unroll
    for (int mt = 0; mt < 2; ++mt)
#pragma unroll
      for (int st = 0; st < 2; ++st)
#pragma unroll
        for (int reg = 0; reg < 4; ++reg) {
          const int R = 16 * mt + 4 * quad + reg;
          const int J = 32 * w + 16 * st + l15;
          const float v = hv[mt][st][reg];
          const unsigned short hi = f2bf(v);
          hAhi[R * KA + J] = hi;
          hAlo[R * KA + J] = f2bf(v - bflo(hi));
          __builtin_nontemporal_store(hi,
              &hDec[((size_t)(l * S8 + s) * BATCH + b0 + R) * HDIM + J]);
        }
    // hd = h . wfo1 in fp32 from registers
    {
      float part[8];
#pragma unroll
      for (int mt = 0; mt < 2; ++mt)
#pragma unroll
        for (int reg = 0; reg < 4; ++reg) {
          const int J0 = 32 * w + l15;
          part[mt * 4 + reg] = hv[mt][0][reg] * wfoS[J0] + hv[mt][1][reg] * wfoS[J0 + 16];
        }
#pragma unroll
      for (int i = 0; i < 8; ++i) {
        float v = part[i];
        v += __shfl_xor(v, 1, 16);
        v += __shfl_xor(v, 2, 16);
        v += __shfl_xor(v, 4, 16);
        v += __shfl_xor(v, 8, 16);
        part[i] = v;
      }
      if (l15 == 0) {
#pragma unroll
        for (int mt = 0; mt < 2; ++mt)
#pragma unroll
          for (int reg = 0; reg < 4; ++reg)
            scrR[(16 * mt + 4 * quad + reg) * 8 + w] = part[mt * 4 + reg];
      }
    }
    __syncthreads();
    if (tid < DBT) {
      float a = 0.f;
#pragma unroll
      for (int p = 0; p < 8; ++p) a += scrR[tid * 8 + p];
      hdPart[((size_t)l * S8 + s) * BATCH + b0 + tid] = a;
    }
    // no extra barrier: scrR's next write is after next iter's first sync
  }
}

// =============== PHASE B: attention + output, fully parallel ===============
__global__ __launch_bounds__(256) void attn_phase(
    const unsigned* __restrict__ hEnc, const unsigned short* __restrict__ hDec,
    const bf16x8* __restrict__ AMvF,
    const float* __restrict__ kbv, const float* __restrict__ cbias,
    const float* __restrict__ mvw,
    const float* __restrict__ Wfo, const float* __restrict__ bfo,
    const float* __restrict__ hdPart,
    float* __restrict__ douts)
{
  __shared__ unsigned short kpL[TENC][16][KA];  // 101.4 KB
  __shared__ float scr[16 * TENC * 17];         // 13.1 KB
  __shared__ float sc[16][TENC];
  __shared__ float kbs[TENC][16];
  __shared__ float vw[TENC][16];

  const int s = blockIdx.y, b0 = blockIdx.x * 16;
  const int tid = threadIdx.x;
  const int w = tid >> 6, lane = tid & 63, l15 = lane & 15, quad = lane >> 4;

  const bf16x8* amv = AMvF + (size_t)s * 8 * 32 * 64;
  const float* kvv = kbv + s * 256;
  const float* mvv = mvw + s * 256;
  const float* cbs = cbias + s * 256;
  const float* wfo = Wfo + s * 512;
  const float bfos = bfo[s];

  float cw = 0.f;
  for (int e = 0; e < 256; ++e) cw = fmaf(cbs[e], wfo[256 + e], cw);

  // --- kp[t] = P . h_enc[t] via MFMA (hi+lo A); rows via l15, nt = 4w+c ---
  for (int t = 0; t < TENC; ++t) {
    f32x4 acc[4];
#pragma unroll
    for (int c = 0; c < 4; ++c) acc[c] = (f32x4){0.f, 0.f, 0.f, 0.f};
    for (int ks = 0; ks < 8; ++ks) {
      const unsigned* hp = hEnc + ((size_t)(t * S8 + s) * BATCH + b0 + l15) * HDIM
                         + ks * 32 + quad * 8;
      union { bf16x8 v; unsigned short e[8]; } uh, ul;
#pragma unroll
      for (int j = 0; j < 8; ++j) {
        const unsigned u = hp[j];
        uh.e[j] = (unsigned short)u;
        ul.e[j] = (unsigned short)(u >> 16);
      }
#pragma unroll
      for (int c = 0; c < 4; ++c) {
        const int nt = w * 4 + c;
        const bf16x8 b = amv[(ks * 32 + nt) * 64 + lane];
        MFMA(acc[c], uh.v, b); MFMA(acc[c], ul.v, b);
      }
    }
#pragma unroll
    for (int c = 0; c < 4; ++c)
#pragma unroll
      for (int reg = 0; reg < 4; ++reg)
        kpL[t][4 * quad + reg][(w * 4 + c) * 16 + l15] = f2bf(acc[c][reg]);
  }
  // --- kbs / vw folds from h_enc (hi+lo floats) ---
  for (int t = 0; t < TENC; ++t) {
    const int row = tid >> 4, p = tid & 15;
    const unsigned* hp = hEnc + ((size_t)(t * S8 + s) * BATCH + b0 + row) * HDIM + p * 16;
    float a = 0.f, b = 0.f;
#pragma unroll
    for (int k = 0; k < 16; ++k) {
      const unsigned u = hp[k];
      const float h = bflo(u) + bfhi(u);
      a = fmaf(kvv[p * 16 + k], h, a);
      b = fmaf(mvv[p * 16 + k], h, b);
    }
    scr[row * 34 + p] = a;
    scr[row * 34 + 17 + p] = b;
    __syncthreads();
    if (tid < 16) {
      float sa = 0.f, sb = 0.f;
#pragma unroll
      for (int p2 = 0; p2 < 16; ++p2) { sa += scr[tid * 34 + p2]; sb += scr[tid * 34 + 17 + p2]; }
      kbs[t][tid] = sa;
      vw[t][tid] = sb;
    }
    __syncthreads();
  }

  // --- per-l scores/softmax/out ---
  for (int l = 0; l < LDEC; ++l) {
    const int row = tid & 15, pp = tid >> 4;
    float hh[16];
    {
      const unsigned short* hp = hDec + ((size_t)(l * S8 + s) * BATCH + b0 + row) * HDIM + pp * 16;
      const uint4 q0 = *(const uint4*)hp;
      const uint4 q1 = *(const uint4*)(hp + 8);
      UNPS(hh, 0, q0);
      UNPS(hh, 8, q1);
    }
#pragma unroll 2
    for (int t = 0; t < TENC; ++t) {
      const uint4 q0 = *(const uint4*)&kpL[t][row][pp * 16];
      const uint4 q1 = *(const uint4*)&kpL[t][row][pp * 16 + 8];
      float a = 0.f;
      { const float* hp8 = &hh[0]; DOT8(a, q0, hp8); }
      { const float* hp8 = &hh[8]; DOT8(a, q1, hp8); }
      scr[(row * TENC + t) * 17 + pp] = a;
    }
    __syncthreads();
    if (tid < 192) {
      const int r2 = tid & 15, t2 = tid >> 4;
      float a = kbs[t2][r2];
#pragma unroll
      for (int p2 = 0; p2 < 16; ++p2) a += scr[(r2 * TENC + t2) * 17 + p2];
      sc[r2][t2] = a * SCALE_ATTN;
    }
    __syncthreads();
    if (tid < 16) {
      float m = sc[tid][0];
#pragma unroll
      for (int t2 = 1; t2 < TENC; ++t2) m = fmaxf(m, sc[tid][t2]);
      float e[TENC], sum = 0.f;
#pragma unroll
      for (int t2 = 0; t2 < TENC; ++t2) { e[t2] = expf(sc[tid][t2] - m); sum += e[t2]; }
      const float inv = 1.0f / sum;
      float av = 0.f;
#pragma unroll
      for (int t2 = 0; t2 < TENC; ++t2) av = fmaf(e[t2] * inv, vw[t2][tid], av);
      const float hd = hdPart[((size_t)l * S8 + s) * BATCH + b0 + tid];
      douts[((size_t)l * S8 + s) * BATCH + b0 + tid] = hd + av + cw + bfos;
    }
    __syncthreads();
  }
}

// ---------------- final fc over streams ----------------
__global__ void final_fc(const float* __restrict__ douts, const float* __restrict__ Wfc,
                         const float* __restrict__ bfc, float* __restrict__ out) {
  int idx = blockIdx.x * 256 + threadIdx.x;
  if (idx >= BATCH * LDEC) return;
  int b = idx / LDEC, l = idx - b * LDEC;
  float a = bfc[0];
#pragma unroll
  for (int s = 0; s < S8; ++s)
    a = fmaf(douts[((size_t)l * S8 + s) * BATCH + b], Wfc[s], a);
  out[idx] = a;
}

extern "C" void kernel_launch(void* const* d_in, const int* in_sizes, int n_in,
                              void* d_out, int out_size, void* d_ws, size_t ws_size,
                              hipStream_t stream) {
  const float* x          = (const float*)d_in[0];
  const float* tgt        = (const float*)d_in[1];
  const float* W_ih_e     = (const float*)d_in[2];
  const float* W_hh_e     = (const float*)d_in[3];
  const float* b_ih_e     = (const float*)d_in[4];
  const float* b_hh_e     = (const float*)d_in[5];
  const float* W_ih_d     = (const float*)d_in[6];
  const float* W_hh_d     = (const float*)d_in[7];
  const float* b_ih_d     = (const float*)d_in[8];
  const float* b_hh_d     = (const float*)d_in[9];
  const float* W_in_attn  = (const float*)d_in[10];
  const float* b_in_attn  = (const float*)d_in[11];
  const float* W_out_attn = (const float*)d_in[12];
  const float* b_out_attn = (const float*)d_in[13];
  const float* W_fcout    = (const float*)d_in[14];
  const float* b_fcout    = (const float*)d_in[15];
  const float* W_fc       = (const float*)d_in[16];
  const float* b_fc       = (const float*)d_in[17];

  char* wsb = (char*)d_ws;
  size_t off = 0;
  auto alloc = [&](size_t bytes) {
    void* p = wsb + off; off += (bytes + 255) & ~(size_t)255; return p;
  };
  float*  douts = (float*)alloc((size_t)LDEC * S8 * BATCH * 4);
  float*  decin = (float*)alloc((size_t)LDEC * BATCH * 4);
  float*  hdPart= (float*)alloc((size_t)LDEC * S8 * BATCH * 4);
  float*  Pmat  = (float*)alloc((size_t)S8 * 256 * 256 * 4);
  float*  Mvmat = (float*)alloc((size_t)S8 * 256 * 256 * 4);
  float*  WoT   = (float*)alloc((size_t)S8 * 256 * 256 * 4);
  bf16x8* WxH   = (bf16x8*)alloc((size_t)S8 * 10 * 64 * 64 * 16);
  bf16x8* WxL   = (bf16x8*)alloc((size_t)S8 * 10 * 64 * 64 * 16);
  bf16x8* WeH   = (bf16x8*)alloc((size_t)S8 * 8 * 64 * 64 * 16);
  bf16x8* WeL   = (bf16x8*)alloc((size_t)S8 * 8 * 64 * 64 * 16);
  bf16x8* WdH   = (bf16x8*)alloc((size_t)S8 * 8 * 64 * 64 * 16);
  bf16x8* WdL   = (bf16x8*)alloc((size_t)S8 * 8 * 64 * 64 * 16);
  bf16x8* AMvF  = (bf16x8*)alloc((size_t)S8 * 8 * 32 * 64 * 16);
  float*  kbv   = (float*)alloc((size_t)S8 * 256 * 4);
  float*  cbias = (float*)alloc((size_t)S8 * 256 * 4);
  float*  mvw   = (float*)alloc((size_t)S8 * 256 * 4);
  float*  beF   = (float*)alloc((size_t)S8 * 1024 * 4);
  float*  bdF   = (float*)alloc((size_t)S8 * 1024 * 4);
  unsigned* hEnc = (unsigned*)alloc((size_t)TENC * S8 * BATCH * HDIM * 4);             // 100.7 MB
  unsigned short* hDec = (unsigned short*)alloc((size_t)LDEC * S8 * BATCH * HDIM * 2); // 201.3 MB
  if (off > ws_size) {
    fprintf(stderr, "kernel_launch: ws too small: need %zu bytes, have %zu\n", off, ws_size);
    return;
  }

  // ---- one-time weight preparation ----
  transpose_k<<<dim3(8, 8, S8), 256, 0, stream>>>(W_out_attn, WoT, 256, 256);
  fold_gemm<<<dim3(8, S8), 256, 0, stream>>>(W_in_attn, (size_t)768 * 256,
                                             W_in_attn + 256 * 256, (size_t)768 * 256,
                                             Pmat, (size_t)256 * 256);
  fold_gemm<<<dim3(8, S8), 256, 0, stream>>>(WoT, (size_t)256 * 256,
                                             W_in_attn + 2 * 256 * 256, (size_t)768 * 256,
                                             Mvmat, (size_t)256 * 256);
  pack_hl<<<dim3(64, 10, S8), 64, 0, stream>>>(W_ih_e, FDIM, 10, WxH, WxL);
  pack_hl<<<dim3(64, 8, S8), 64, 0, stream>>>(W_hh_e, 256, 8, WeH, WeL);
  pack_hl<<<dim3(64, 8, S8), 64, 0, stream>>>(W_hh_d, 256, 8, WdH, WdL);
  pack_s<<<dim3(16, 8, S8), 64, 0, stream>>>(Pmat, 0, AMvF);
  fold_vec2<<<S8, 256, 0, stream>>>(W_in_attn, b_in_attn, W_out_attn, b_out_attn, kbv, cbias);
  fold_mvw<<<S8, 256, 0, stream>>>(Mvmat, W_fcout, mvw);
  fold_bias<<<(S8 * 1024 + 255) / 256, 256, 0, stream>>>(b_ih_e, b_hh_e, beF, S8 * 1024);
  fold_bias<<<(S8 * 1024 + 255) / 256, 256, 0, stream>>>(b_ih_d, b_hh_d, bdF, S8 * 1024);
  build_decin<<<(LDEC * BATCH + 255) / 256, 256, 0, stream>>>(x, tgt, decin);

  // Phase A: the recurrence only (grid 256, 512 thr, 1 round — R14 verified best)
  rec_phase<<<256, 512, 0, stream>>>(
      x, WxH, WxL, WeH, WeL, WdH, WdL, beF, bdF, W_ih_d, W_fcout, decin,
      hEnc, hDec, hdPart);

  // Phase B: attention + outputs (fully parallel over l and batch)
  attn_phase<<<dim3(64, S8), 256, 0, stream>>>(
      hEnc, hDec, AMvF, kbv, cbias, mvw, W_fcout, b_fcout, hdPart, douts);

  final_fc<<<(BATCH * LDEC + 255) / 256, 256, 0, stream>>>(douts, W_fc, b_fc, (float*)d_out);
}

// Round 18
// 2713.450 us; speedup vs baseline: 1.6880x; 1.0216x over previous
//
#include <hip/hip_runtime.h>
#include <cstdio>
#include <cstdint>

#define S8     8
#define TENC   12
#define HDIM   256
#define FDIM   316
#define BATCH  1024
#define LDEC   48
#define DBT    32           // batch rows per block in rec_phase; grid 256 = 1 block/CU
#define KA     264          // hA row stride in shorts (16B-aligned rows)
#define SCALE_ATTN 0.0625f  // 1/sqrt(256)

typedef short bf16x8 __attribute__((ext_vector_type(8)));
typedef float f32x4  __attribute__((ext_vector_type(4)));

__device__ __forceinline__ float sigf(float x) { return 1.0f / (1.0f + expf(-x)); }

__device__ __forceinline__ unsigned short f2bf(float f) {
  unsigned u = __builtin_bit_cast(unsigned, f);
  unsigned r = (u + 0x7fffu + ((u >> 16) & 1u)) >> 16;   // RNE
  return (unsigned short)r;
}
__device__ __forceinline__ float bflo(unsigned u) {
  return __builtin_bit_cast(float, u << 16);
}
__device__ __forceinline__ float bfhi(unsigned u) {
  return __builtin_bit_cast(float, u & 0xffff0000u);
}

#define MFMA(acc, a, b) acc = __builtin_amdgcn_mfma_f32_16x16x32_bf16(a, b, acc, 0, 0, 0)

// DOT8: q = 4 u32 holding 8 bf16 (lo/hi pairs), hp = 8 floats
#define DOT8(a, q, hp) \
  a = fmaf(bflo(q.x), hp[0], a); a = fmaf(bfhi(q.x), hp[1], a); \
  a = fmaf(bflo(q.y), hp[2], a); a = fmaf(bfhi(q.y), hp[3], a); \
  a = fmaf(bflo(q.z), hp[4], a); a = fmaf(bfhi(q.z), hp[5], a); \
  a = fmaf(bflo(q.w), hp[6], a); a = fmaf(bfhi(q.w), hp[7], a);

// UNPS: 4 u32 (= 8 ushorts of a bf16 array) -> 8 floats
#define UNPS(dst, off, q) \
  dst[off+0] = bflo(q.x); dst[off+1] = bfhi(q.x); \
  dst[off+2] = bflo(q.y); dst[off+3] = bfhi(q.y); \
  dst[off+4] = bflo(q.z); dst[off+5] = bfhi(q.z); \
  dst[off+6] = bflo(q.w); dst[off+7] = bfhi(q.w);

// ---------------- transpose: in [S][R][C] -> out [S][C][R] ----------------
__global__ __launch_bounds__(256) void transpose_k(const float* __restrict__ in,
                                                   float* __restrict__ out,
                                                   int R, int C) {
  __shared__ float tile[32][33];
  const int s = blockIdx.z;
  const size_t base = (size_t)s * R * C;
  const int r0 = blockIdx.y * 32, c0 = blockIdx.x * 32;
  const int tx = threadIdx.x & 31, ty = threadIdx.x >> 5;
  for (int i = ty; i < 32; i += 8) {
    int r = r0 + i, c = c0 + tx;
    if (r < R && c < C) tile[i][tx] = in[base + (size_t)r * C + c];
  }
  __syncthreads();
  for (int i = ty; i < 32; i += 8) {
    int c = c0 + i, r = r0 + tx;
    if (c < C && r < R) out[base + (size_t)c * R + r] = tile[tx][i];
  }
}

// ---- fold GEMM: out[s][r][col] = sum_e A[s][e][r] * B[s][e][col], 256x256, K=256 ----
__global__ __launch_bounds__(256) void fold_gemm(const float* __restrict__ A, size_t sA,
                                                 const float* __restrict__ Bm, size_t sB,
                                                 float* __restrict__ out, size_t sO) {
  const int s = blockIdx.y, r0 = blockIdx.x * 32, col = threadIdx.x;
  A += (size_t)s * sA; Bm += (size_t)s * sB; out += (size_t)s * sO;
  float acc[32] = {};
  for (int e = 0; e < HDIM; ++e) {
    const float bvv = Bm[(size_t)e * HDIM + col];
#pragma unroll
    for (int r = 0; r < 32; ++r) acc[r] = fmaf(A[(size_t)e * HDIM + r0 + r], bvv, acc[r]);
  }
  for (int r = 0; r < 32; ++r) out[(size_t)(r0 + r) * HDIM + col] = acc[r];
}

// ---- pack gate weights [S][1024][Ksrc] into B-fragment layout, hi+lo bf16 ----
__global__ __launch_bounds__(64) void pack_hl(const float* __restrict__ src, int Ksrc, int ksT,
                                              bf16x8* __restrict__ outhi,
                                              bf16x8* __restrict__ outlo) {
  const int s = blockIdx.z, ks = blockIdx.y, nt = blockIdx.x;
  const int lane = threadIdx.x, l15 = lane & 15, quad = lane >> 4;
  const int n = nt * 16 + l15, kb = ks * 32 + quad * 8;
  const float* row = src + ((size_t)s * 1024 + n) * Ksrc;
  union { bf16x8 v; unsigned short e[8]; } h, l;
#pragma unroll
  for (int j = 0; j < 8; ++j) {
    const int k = kb + j;
    const float v = (k < Ksrc) ? row[k] : 0.f;
    const unsigned short hi = f2bf(v);
    h.e[j] = hi;
    l.e[j] = f2bf(v - bflo(hi));
  }
  const size_t idx = (((size_t)s * ksT + ks) * 64 + nt) * 64 + lane;
  outhi[idx] = h.v;
  outlo[idx] = l.v;
}

// ---- pack attention fold matrix P [S][256][256] into B-frag (single bf16), nt 0..15 ----
__global__ __launch_bounds__(64) void pack_s(const float* __restrict__ src, int ntOff,
                                             bf16x8* __restrict__ out) {
  const int s = blockIdx.z, ks = blockIdx.y, nt = blockIdx.x;
  const int lane = threadIdx.x, l15 = lane & 15, quad = lane >> 4;
  const int n = nt * 16 + l15, kb = ks * 32 + quad * 8;
  const float* row = src + ((size_t)s * 256 + n) * 256;
  union { bf16x8 v; unsigned short e[8]; } h;
#pragma unroll
  for (int j = 0; j < 8; ++j) h.e[j] = f2bf(row[kb + j]);
  out[(((size_t)s * 8 + ks) * 32 + ntOff + nt) * 64 + lane] = h.v;
}

// ---- fold vectors: kbv = Wk^T bq ; cbias = Wo bv + b_out ----
__global__ __launch_bounds__(256) void fold_vec2(const float* __restrict__ Win,
                                                 const float* __restrict__ bin,
                                                 const float* __restrict__ Wout,
                                                 const float* __restrict__ bout,
                                                 float* __restrict__ kbv,
                                                 float* __restrict__ cbias) {
  const int s = blockIdx.x, t = threadIdx.x;
  const float* bq = bin + s * 768;
  const float* bv = bin + s * 768 + 512;
  float a0 = 0.f, a1 = 0.f;
  for (int e = 0; e < 256; ++e) {
    a0 = fmaf(Win[((size_t)s * 768 + 256 + e) * 256 + t], bq[e], a0);
    a1 = fmaf(Wout[((size_t)s * 256 + t) * 256 + e], bv[e], a1);
  }
  kbv[s * 256 + t] = a0;
  cbias[s * 256 + t] = a1 + bout[s * 256 + t];
}

// ---- mvw[s][k] = sum_o wfo2[s][o] * Mv[s][o][k] ----
__global__ __launch_bounds__(256) void fold_mvw(const float* __restrict__ Mv,
                                                const float* __restrict__ Wfo,
                                                float* __restrict__ mvw) {
  const int s = blockIdx.x, k = threadIdx.x;
  float a = 0.f;
  for (int o = 0; o < 256; ++o)
    a = fmaf(Wfo[s * 512 + 256 + o], Mv[((size_t)s * 256 + o) * 256 + k], a);
  mvw[s * 256 + k] = a;
}

__global__ void fold_bias(const float* __restrict__ a, const float* __restrict__ b,
                          float* __restrict__ o, int n) {
  int i = blockIdx.x * 256 + threadIdx.x;
  if (i < n) o[i] = a[i] + b[i];
}

__global__ void build_decin(const float* __restrict__ x, const float* __restrict__ tgt,
                            float* __restrict__ dec_in) {
  int idx = blockIdx.x * 256 + threadIdx.x;
  if (idx >= LDEC * BATCH) return;
  int l = idx >> 10, b = idx & 1023;
  dec_in[idx] = (l == 0) ? x[(size_t)b * 96 * FDIM + 95 * FDIM]
                         : tgt[(size_t)b * LDEC + (l - 1)];
}

// =============== PHASE A: the recurrence, and ONLY the recurrence ===============
// R14 configuration — verified best (rec ~2100-2170 us). DO NOT PERTURB (R15/R16:
// any register-schedule perturbation regressed; this codegen is a local optimum).
__global__ __launch_bounds__(512) void rec_phase(
    const float* __restrict__ x,
    const bf16x8* __restrict__ WxH, const bf16x8* __restrict__ WxL,
    const bf16x8* __restrict__ WeH, const bf16x8* __restrict__ WeL,
    const bf16x8* __restrict__ WdH, const bf16x8* __restrict__ WdL,
    const float* __restrict__ be, const float* __restrict__ bd,
    const float* __restrict__ wihd, const float* __restrict__ Wfo,
    const float* __restrict__ decin,
    unsigned* __restrict__ hEnc,         // [t][s][b][e] packed hi|lo
    unsigned short* __restrict__ hDec,   // [l][s][b][e] bf16 hi
    float* __restrict__ hdPart)          // [l][s][b] = h_dec . wfo1 (fp32)
{
  __shared__ unsigned short hAhi[DBT * KA];   // 16.9 KB
  __shared__ unsigned short hAlo[DBT * KA];   // 16.9 KB
  __shared__ float beS[1024];                 // 4 KB
  __shared__ float bdS[1024];                 // 4 KB
  __shared__ float wdS[1024];                 // 4 KB
  __shared__ float wfoS[256];                 // 1 KB
  __shared__ float scrR[DBT * 8];             // 1 KB (hd partials)

  const int bid = blockIdx.x;
  const int s = bid & 7, b0 = (bid >> 3) * DBT;
  const int tid = threadIdx.x;
  const int w = tid >> 6, lane = tid & 63, l15 = lane & 15, quad = lane >> 4;

  for (int i = tid; i < DBT * KA; i += 512) { hAhi[i] = 0; hAlo[i] = 0; }
  for (int i = tid; i < 1024; i += 512) {
    beS[i] = be[s * 1024 + i];
    bdS[i] = bd[s * 1024 + i];
    wdS[i] = wihd[s * 1024 + i];
  }
  if (tid < 256) wfoS[tid] = Wfo[s * 512 + tid];

  float cst[2][2][4];
#pragma unroll
  for (int a = 0; a < 2; ++a)
#pragma unroll
    for (int b = 0; b < 2; ++b)
#pragma unroll
      for (int r = 0; r < 4; ++r) cst[a][b][r] = 0.f;

  const bf16x8* wxh = WxH + (size_t)s * 10 * 64 * 64;
  const bf16x8* wxl = WxL + (size_t)s * 10 * 64 * 64;
  const bf16x8* weh = WeH + (size_t)s * 8 * 64 * 64;
  const bf16x8* wel = WeL + (size_t)s * 8 * 64 * 64;
  const bf16x8* wdh = WdH + (size_t)s * 8 * 64 * 64;
  const bf16x8* wdl = WdL + (size_t)s * 8 * 64 * 64;

  __syncthreads();

  // ===================== encoder =====================
  for (int t = 0; t < TENC; ++t) {
    f32x4 acc[2][2][4];
#pragma unroll
    for (int mt = 0; mt < 2; ++mt)
#pragma unroll
      for (int st = 0; st < 2; ++st)
#pragma unroll
        for (int c = 0; c < 4; ++c) acc[mt][st][c] = (f32x4){0.f, 0.f, 0.f, 0.f};

    const size_t xoff = (size_t)(s * TENC + t) * FDIM;
    for (int ks = 0; ks < 10; ++ks) {
      bf16x8 axh[2], axl[2];
#pragma unroll
      for (int mt = 0; mt < 2; ++mt) {
        const f32x4* xr = (const f32x4*)(x + (size_t)(b0 + 16 * mt + l15) * (96 * FDIM)
                                         + xoff + ks * 32 + quad * 8);
        const f32x4 v0 = __builtin_nontemporal_load(xr);
        f32x4 v1;
        if (ks == 9 && quad == 3) v1 = (f32x4){0.f, 0.f, 0.f, 0.f};
        else v1 = __builtin_nontemporal_load(xr + 1);
        float vv[8];
#pragma unroll
        for (int j = 0; j < 4; ++j) { vv[j] = v0[j]; vv[4 + j] = v1[j]; }
        union { bf16x8 v; unsigned short e[8]; } uh, ul;
#pragma unroll
        for (int j = 0; j < 8; ++j) {
          const unsigned short hi = f2bf(vv[j]);
          uh.e[j] = hi;
          ul.e[j] = f2bf(vv[j] - bflo(hi));
        }
        axh[mt] = uh.v; axl[mt] = ul.v;
      }
#pragma unroll
      for (int st = 0; st < 2; ++st)
#pragma unroll
        for (int c = 0; c < 4; ++c) {
          const int nt = c * 16 + 2 * w + st;
          const bf16x8 bh = wxh[(ks * 64 + nt) * 64 + lane];
          const bf16x8 bl = wxl[(ks * 64 + nt) * 64 + lane];
          MFMA(acc[0][st][c], axh[0], bh); MFMA(acc[0][st][c], axh[0], bl); MFMA(acc[0][st][c], axl[0], bh);
          MFMA(acc[1][st][c], axh[1], bh); MFMA(acc[1][st][c], axh[1], bl); MFMA(acc[1][st][c], axl[1], bh);
        }
    }
#pragma unroll 2
    for (int ks = 0; ks < 8; ++ks) {
      bf16x8 ah[2], al[2];
#pragma unroll
      for (int mt = 0; mt < 2; ++mt) {
        const int ao = (16 * mt + l15) * KA + ks * 32 + quad * 8;
        ah[mt] = *(const bf16x8*)&hAhi[ao];
        al[mt] = *(const bf16x8*)&hAlo[ao];
      }
#pragma unroll
      for (int st = 0; st < 2; ++st)
#pragma unroll
        for (int c = 0; c < 4; ++c) {
          const int nt = c * 16 + 2 * w + st;
          const bf16x8 bh = weh[(ks * 64 + nt) * 64 + lane];
          const bf16x8 bl = wel[(ks * 64 + nt) * 64 + lane];
          MFMA(acc[0][st][c], ah[0], bh); MFMA(acc[0][st][c], ah[0], bl); MFMA(acc[0][st][c], al[0], bh);
          MFMA(acc[1][st][c], ah[1], bh); MFMA(acc[1][st][c], ah[1], bl); MFMA(acc[1][st][c], al[1], bh);
        }
    }
    // pointwise LSTM -- gate biases from LDS table
    float hv[2][2][4];
#pragma unroll
    for (int st = 0; st < 2; ++st) {
      const int J0 = 32 * w + 16 * st + l15;
      const float g0 = beS[J0];
      const float g1 = beS[256 + J0];
      const float g2 = beS[512 + J0];
      const float g3 = beS[768 + J0];
#pragma unroll
      for (int mt = 0; mt < 2; ++mt)
#pragma unroll
        for (int reg = 0; reg < 4; ++reg) {
          const float gi = sigf(acc[mt][st][0][reg] + g0);
          const float gf = sigf(acc[mt][st][1][reg] + g1);
          const float gg = tanhf(acc[mt][st][2][reg] + g2);
          const float go = sigf(acc[mt][st][3][reg] + g3);
          const float cn = fmaf(gf, cst[mt][st][reg], gi * gg);
          cst[mt][st][reg] = cn;
          hv[mt][st][reg] = go * tanhf(cn);
        }
    }
    __syncthreads();
#pragma unroll
    for (int mt = 0; mt < 2; ++mt)
#pragma unroll
      for (int st = 0; st < 2; ++st)
#pragma unroll
        for (int reg = 0; reg < 4; ++reg) {
          const int R = 16 * mt + 4 * quad + reg;
          const int J = 32 * w + 16 * st + l15;
          const float v = hv[mt][st][reg];
          const unsigned short hi = f2bf(v);
          const unsigned short lo = f2bf(v - bflo(hi));
          hAhi[R * KA + J] = hi;
          hAlo[R * KA + J] = lo;
          __builtin_nontemporal_store((unsigned)hi | ((unsigned)lo << 16),
              &hEnc[((size_t)(t * S8 + s) * BATCH + b0 + R) * HDIM + J]);
        }
    __syncthreads();
  }

  // ===================== decoder (LSTM only + fp32 hd dot) =====================
  for (int l = 0; l < LDEC; ++l) {
    f32x4 acc[2][2][4];
#pragma unroll
    for (int mt = 0; mt < 2; ++mt)
#pragma unroll
      for (int st = 0; st < 2; ++st)
#pragma unroll
        for (int c = 0; c < 4; ++c) acc[mt][st][c] = (f32x4){0.f, 0.f, 0.f, 0.f};

#pragma unroll 2
    for (int ks = 0; ks < 8; ++ks) {
      bf16x8 ah[2], al[2];
#pragma unroll
      for (int mt = 0; mt < 2; ++mt) {
        const int ao = (16 * mt + l15) * KA + ks * 32 + quad * 8;
        ah[mt] = *(const bf16x8*)&hAhi[ao];
        al[mt] = *(const bf16x8*)&hAlo[ao];
      }
#pragma unroll
      for (int st = 0; st < 2; ++st)
#pragma unroll
        for (int c = 0; c < 4; ++c) {
          const int nt = c * 16 + 2 * w + st;
          const bf16x8 bh = wdh[(ks * 64 + nt) * 64 + lane];
          const bf16x8 bl = wdl[(ks * 64 + nt) * 64 + lane];
          MFMA(acc[0][st][c], ah[0], bh); MFMA(acc[0][st][c], ah[0], bl); MFMA(acc[0][st][c], al[0], bh);
          MFMA(acc[1][st][c], ah[1], bh); MFMA(acc[1][st][c], ah[1], bl); MFMA(acc[1][st][c], al[1], bh);
        }
    }
    // pointwise LSTM -- bd/wd from LDS tables
    float hv[2][2][4];
#pragma unroll
    for (int st = 0; st < 2; ++st) {
      const int J0 = 32 * w + 16 * st + l15;
      const float b0g = bdS[J0];
      const float b1g = bdS[256 + J0];
      const float b2g = bdS[512 + J0];
      const float b3g = bdS[768 + J0];
      const float w0g = wdS[J0];
      const float w1g = wdS[256 + J0];
      const float w2g = wdS[512 + J0];
      const float w3g = wdS[768 + J0];
#pragma unroll
      for (int mt = 0; mt < 2; ++mt)
#pragma unroll
        for (int reg = 0; reg < 4; ++reg) {
          const int R = 16 * mt + 4 * quad + reg;
          const float it = decin[(size_t)l * BATCH + b0 + R];
          const float gi = sigf(fmaf(it, w0g, acc[mt][st][0][reg] + b0g));
          const float gf = sigf(fmaf(it, w1g, acc[mt][st][1][reg] + b1g));
          const float gg = tanhf(fmaf(it, w2g, acc[mt][st][2][reg] + b2g));
          const float go = sigf(fmaf(it, w3g, acc[mt][st][3][reg] + b3g));
          const float cn = fmaf(gf, cst[mt][st][reg], gi * gg);
          cst[mt][st][reg] = cn;
          hv[mt][st][reg] = go * tanhf(cn);
        }
    }
    __syncthreads();
#pragma unroll
    for (int mt = 0; mt < 2; ++mt)
#pragma unroll
      for (int st = 0; st < 2; ++st)
#pragma unroll
        for (int reg = 0; reg < 4; ++reg) {
          const int R = 16 * mt + 4 * quad + reg;
          const int J = 32 * w + 16 * st + l15;
          const float v = hv[mt][st][reg];
          const unsigned short hi = f2bf(v);
          hAhi[R * KA + J] = hi;
          hAlo[R * KA + J] = f2bf(v - bflo(hi));
          __builtin_nontemporal_store(hi,
              &hDec[((size_t)(l * S8 + s) * BATCH + b0 + R) * HDIM + J]);
        }
    // hd = h . wfo1 in fp32 from registers
    {
      float part[8];
#pragma unroll
      for (int mt = 0; mt < 2; ++mt)
#pragma unroll
        for (int reg = 0; reg < 4; ++reg) {
          const int J0 = 32 * w + l15;
          part[mt * 4 + reg] = hv[mt][0][reg] * wfoS[J0] + hv[mt][1][reg] * wfoS[J0 + 16];
        }
#pragma unroll
      for (int i = 0; i < 8; ++i) {
        float v = part[i];
        v += __shfl_xor(v, 1, 16);
        v += __shfl_xor(v, 2, 16);
        v += __shfl_xor(v, 4, 16);
        v += __shfl_xor(v, 8, 16);
        part[i] = v;
      }
      if (l15 == 0) {
#pragma unroll
        for (int mt = 0; mt < 2; ++mt)
#pragma unroll
          for (int reg = 0; reg < 4; ++reg)
            scrR[(16 * mt + 4 * quad + reg) * 8 + w] = part[mt * 4 + reg];
      }
    }
    __syncthreads();
    if (tid < DBT) {
      float a = 0.f;
#pragma unroll
      for (int p = 0; p < 8; ++p) a += scrR[tid * 8 + p];
      hdPart[((size_t)l * S8 + s) * BATCH + b0 + tid] = a;
    }
    // no extra barrier: scrR's next write is after next iter's first sync
  }
}

// =============== PHASE B: attention + output, 1024 threads ===============
// 16 waves: kp production one nt-tile per wave (1 barrier); kbs/vw fold one
// wave per row with 64-lane shfl reduce (0 barriers); l-loop processes 2
// decoder steps per iteration (3 barriers x 24 iters, was 4 x 48).
// Granted arch VGPR at 1024 thr = 64; per-thread state here is small (~35).
__global__ __launch_bounds__(1024) void attn_phase(
    const unsigned* __restrict__ hEnc, const unsigned short* __restrict__ hDec,
    const bf16x8* __restrict__ AMvF,
    const float* __restrict__ kbv, const float* __restrict__ cbias,
    const float* __restrict__ mvw,
    const float* __restrict__ Wfo, const float* __restrict__ bfo,
    const float* __restrict__ hdPart,
    float* __restrict__ douts)
{
  __shared__ unsigned short kpL[TENC][16][KA];   // 101.4 KB
  __shared__ float scr2[2 * 16 * TENC * 33];     // 50.7 KB (score partials, 2 l)
  __shared__ float sc[2][16][TENC];              // 1.5 KB
  __shared__ float kbs[TENC][16];                // 0.75 KB
  __shared__ float vw[TENC][16];                 // 0.75 KB
  // total ~155.1 KB <= 160 KB

  const int s = blockIdx.y, b0 = blockIdx.x * 16;
  const int tid = threadIdx.x;
  const int w = tid >> 6, lane = tid & 63, l15 = lane & 15, quad = lane >> 4;

  const bf16x8* amv = AMvF + (size_t)s * 8 * 32 * 64;
  const float* kvv = kbv + s * 256;
  const float* mvv = mvw + s * 256;
  const float* cbs = cbias + s * 256;
  const float* wfo = Wfo + s * 512;
  const float bfos = bfo[s];

  float cw = 0.f;
  for (int e = 0; e < 256; ++e) cw = fmaf(cbs[e], wfo[256 + e], cw);

  // --- kp[t] = P . h_enc[t] via MFMA; 16 waves, wave w owns nt = w ---
  for (int t = 0; t < TENC; ++t) {
    f32x4 acc = (f32x4){0.f, 0.f, 0.f, 0.f};
    for (int ks = 0; ks < 8; ++ks) {
      const unsigned* hp = hEnc + ((size_t)(t * S8 + s) * BATCH + b0 + l15) * HDIM
                         + ks * 32 + quad * 8;
      union { bf16x8 v; unsigned short e[8]; } uh, ul;
#pragma unroll
      for (int j = 0; j < 8; ++j) {
        const unsigned u = hp[j];
        uh.e[j] = (unsigned short)u;
        ul.e[j] = (unsigned short)(u >> 16);
      }
      const bf16x8 b = amv[(ks * 32 + w) * 64 + lane];
      MFMA(acc, uh.v, b); MFMA(acc, ul.v, b);
    }
#pragma unroll
    for (int reg = 0; reg < 4; ++reg)
      kpL[t][4 * quad + reg][w * 16 + l15] = f2bf(acc[reg]);
  }

  // --- kbs / vw folds: one wave per row, 64-lane shfl reduce, no barriers ---
  {
    const int row = tid >> 6;   // 0..15
    const int p = lane;         // 0..63, 4 elements each
    for (int t = 0; t < TENC; ++t) {
      const unsigned* hp = hEnc + ((size_t)(t * S8 + s) * BATCH + b0 + row) * HDIM + p * 4;
      float a = 0.f, bv = 0.f;
#pragma unroll
      for (int j = 0; j < 4; ++j) {
        const unsigned u = hp[j];
        const float h = bflo(u) + bfhi(u);
        a = fmaf(kvv[p * 4 + j], h, a);
        bv = fmaf(mvv[p * 4 + j], h, bv);
      }
#pragma unroll
      for (int off = 1; off < 64; off <<= 1) {
        a += __shfl_xor(a, off, 64);
        bv += __shfl_xor(bv, off, 64);
      }
      if (lane == 0) { kbs[t][row] = a; vw[t][row] = bv; }
    }
  }
  __syncthreads();   // kpL + kbs + vw ready

  // --- l-loop: 2 decoder steps per iteration ---
  for (int li = 0; li < LDEC / 2; ++li) {
    const int lh = tid >> 9;          // 0 or 1
    const int l = li * 2 + lh;
    const int t2 = tid & 511;
    const int row = t2 & 15, pp = t2 >> 4;   // pp 0..31, chunks of 8
    float hh[8];
    {
      const unsigned short* hp = hDec + ((size_t)(l * S8 + s) * BATCH + b0 + row) * HDIM + pp * 8;
      const uint4 q = *(const uint4*)hp;
      UNPS(hh, 0, q);
    }
#pragma unroll 2
    for (int t = 0; t < TENC; ++t) {
      const uint4 q0 = *(const uint4*)&kpL[t][row][pp * 8];
      float a = 0.f;
      const float* hp8 = hh;
      DOT8(a, q0, hp8);
      scr2[((lh * 16 + row) * TENC + t) * 33 + pp] = a;
    }
    __syncthreads();
    if (t2 < 192) {
      const int r2 = t2 & 15, tt = t2 >> 4;
      float a = kbs[tt][r2];
#pragma unroll
      for (int p2 = 0; p2 < 32; ++p2) a += scr2[((lh * 16 + r2) * TENC + tt) * 33 + p2];
      sc[lh][r2][tt] = a * SCALE_ATTN;
    }
    __syncthreads();
    if (t2 < 16) {
      float m = sc[lh][t2][0];
#pragma unroll
      for (int tt = 1; tt < TENC; ++tt) m = fmaxf(m, sc[lh][t2][tt]);
      float e[TENC], sum = 0.f;
#pragma unroll
      for (int tt = 0; tt < TENC; ++tt) { e[tt] = expf(sc[lh][t2][tt] - m); sum += e[tt]; }
      const float inv = 1.0f / sum;
      float av = 0.f;
#pragma unroll
      for (int tt = 0; tt < TENC; ++tt) av = fmaf(e[tt] * inv, vw[tt][t2], av);
      const float hd = hdPart[((size_t)l * S8 + s) * BATCH + b0 + t2];
      douts[((size_t)l * S8 + s) * BATCH + b0 + t2] = hd + av + cw + bfos;
    }
    __syncthreads();
  }
}

// ---------------- final fc over streams ----------------
__global__ void final_fc(const float* __restrict__ douts, const float* __restrict__ Wfc,
                         const float* __restrict__ bfc, float* __restrict__ out) {
  int idx = blockIdx.x * 256 + threadIdx.x;
  if (idx >= BATCH * LDEC) return;
  int b = idx / LDEC, l = idx - b * LDEC;
  float a = bfc[0];
#pragma unroll
  for (int s = 0; s < S8; ++s)
    a = fmaf(douts[((size_t)l * S8 + s) * BATCH + b], Wfc[s], a);
  out[idx] = a;
}

extern "C" void kernel_launch(void* const* d_in, const int* in_sizes, int n_in,
                              void* d_out, int out_size, void* d_ws, size_t ws_size,
                              hipStream_t stream) {
  const float* x          = (const float*)d_in[0];
  const float* tgt        = (const float*)d_in[1];
  const float* W_ih_e     = (const float*)d_in[2];
  const float* W_hh_e     = (const float*)d_in[3];
  const float* b_ih_e     = (const float*)d_in[4];
  const float* b_hh_e     = (const float*)d_in[5];
  const float* W_ih_d     = (const float*)d_in[6];
  const float* W_hh_d     = (const float*)d_in[7];
  const float* b_ih_d     = (const float*)d_in[8];
  const float* b_hh_d     = (const float*)d_in[9];
  const float* W_in_attn  = (const float*)d_in[10];
  const float* b_in_attn  = (const float*)d_in[11];
  const float* W_out_attn = (const float*)d_in[12];
  const float* b_out_attn = (const float*)d_in[13];
  const float* W_fcout    = (const float*)d_in[14];
  const float* b_fcout    = (const float*)d_in[15];
  const float* W_fc       = (const float*)d_in[16];
  const float* b_fc       = (const float*)d_in[17];

  char* wsb = (char*)d_ws;
  size_t off = 0;
  auto alloc = [&](size_t bytes) {
    void* p = wsb + off; off += (bytes + 255) & ~(size_t)255; return p;
  };
  float*  douts = (float*)alloc((size_t)LDEC * S8 * BATCH * 4);
  float*  decin = (float*)alloc((size_t)LDEC * BATCH * 4);
  float*  hdPart= (float*)alloc((size_t)LDEC * S8 * BATCH * 4);
  float*  Pmat  = (float*)alloc((size_t)S8 * 256 * 256 * 4);
  float*  Mvmat = (float*)alloc((size_t)S8 * 256 * 256 * 4);
  float*  WoT   = (float*)alloc((size_t)S8 * 256 * 256 * 4);
  bf16x8* WxH   = (bf16x8*)alloc((size_t)S8 * 10 * 64 * 64 * 16);
  bf16x8* WxL   = (bf16x8*)alloc((size_t)S8 * 10 * 64 * 64 * 16);
  bf16x8* WeH   = (bf16x8*)alloc((size_t)S8 * 8 * 64 * 64 * 16);
  bf16x8* WeL   = (bf16x8*)alloc((size_t)S8 * 8 * 64 * 64 * 16);
  bf16x8* WdH   = (bf16x8*)alloc((size_t)S8 * 8 * 64 * 64 * 16);
  bf16x8* WdL   = (bf16x8*)alloc((size_t)S8 * 8 * 64 * 64 * 16);
  bf16x8* AMvF  = (bf16x8*)alloc((size_t)S8 * 8 * 32 * 64 * 16);
  float*  kbv   = (float*)alloc((size_t)S8 * 256 * 4);
  float*  cbias = (float*)alloc((size_t)S8 * 256 * 4);
  float*  mvw   = (float*)alloc((size_t)S8 * 256 * 4);
  float*  beF   = (float*)alloc((size_t)S8 * 1024 * 4);
  float*  bdF   = (float*)alloc((size_t)S8 * 1024 * 4);
  unsigned* hEnc = (unsigned*)alloc((size_t)TENC * S8 * BATCH * HDIM * 4);             // 100.7 MB
  unsigned short* hDec = (unsigned short*)alloc((size_t)LDEC * S8 * BATCH * HDIM * 2); // 201.3 MB
  if (off > ws_size) {
    fprintf(stderr, "kernel_launch: ws too small: need %zu bytes, have %zu\n", off, ws_size);
    return;
  }

  // ---- one-time weight preparation ----
  transpose_k<<<dim3(8, 8, S8), 256, 0, stream>>>(W_out_attn, WoT, 256, 256);
  fold_gemm<<<dim3(8, S8), 256, 0, stream>>>(W_in_attn, (size_t)768 * 256,
                                             W_in_attn + 256 * 256, (size_t)768 * 256,
                                             Pmat, (size_t)256 * 256);
  fold_gemm<<<dim3(8, S8), 256, 0, stream>>>(WoT, (size_t)256 * 256,
                                             W_in_attn + 2 * 256 * 256, (size_t)768 * 256,
                                             Mvmat, (size_t)256 * 256);
  pack_hl<<<dim3(64, 10, S8), 64, 0, stream>>>(W_ih_e, FDIM, 10, WxH, WxL);
  pack_hl<<<dim3(64, 8, S8), 64, 0, stream>>>(W_hh_e, 256, 8, WeH, WeL);
  pack_hl<<<dim3(64, 8, S8), 64, 0, stream>>>(W_hh_d, 256, 8, WdH, WdL);
  pack_s<<<dim3(16, 8, S8), 64, 0, stream>>>(Pmat, 0, AMvF);
  fold_vec2<<<S8, 256, 0, stream>>>(W_in_attn, b_in_attn, W_out_attn, b_out_attn, kbv, cbias);
  fold_mvw<<<S8, 256, 0, stream>>>(Mvmat, W_fcout, mvw);
  fold_bias<<<(S8 * 1024 + 255) / 256, 256, 0, stream>>>(b_ih_e, b_hh_e, beF, S8 * 1024);
  fold_bias<<<(S8 * 1024 + 255) / 256, 256, 0, stream>>>(b_ih_d, b_hh_d, bdF, S8 * 1024);
  build_decin<<<(LDEC * BATCH + 255) / 256, 256, 0, stream>>>(x, tgt, decin);

  // Phase A: the recurrence only (grid 256, 512 thr — R14 verified best)
  rec_phase<<<256, 512, 0, stream>>>(
      x, WxH, WxL, WeH, WeL, WdH, WdL, beF, bdF, W_ih_d, W_fcout, decin,
      hEnc, hDec, hdPart);

  // Phase B: attention + outputs (1024 thr, 2 l/iter, wave-reduced folds)
  attn_phase<<<dim3(64, S8), 1024, 0, stream>>>(
      hEnc, hDec, AMvF, kbv, cbias, mvw, W_fcout, b_fcout, hdPart, douts);

  final_fc<<<(BATCH * LDEC + 255) / 256, 256, 0, stream>>>(douts, W_fc, b_fc, (float*)d_out);
}

// Round 19
// 2675.257 us; speedup vs baseline: 1.7121x; 1.0143x over previous
//
#include <hip/hip_runtime.h>
#include <cstdio>
#include <cstdint>

#define S8     8
#define TENC   12
#define HDIM   256
#define FDIM   316
#define BATCH  1024
#define LDEC   48
#define DBT    32           // batch rows per block in rec_phase; grid 256 = 1 block/CU
#define KA     264          // hA row stride in shorts (16B-aligned rows)
#define SCALE_ATTN 0.0625f  // 1/sqrt(256)

typedef short bf16x8 __attribute__((ext_vector_type(8)));
typedef float f32x4  __attribute__((ext_vector_type(4)));

__device__ __forceinline__ float sigf(float x) { return 1.0f / (1.0f + expf(-x)); }

__device__ __forceinline__ unsigned short f2bf(float f) {
  unsigned u = __builtin_bit_cast(unsigned, f);
  unsigned r = (u + 0x7fffu + ((u >> 16) & 1u)) >> 16;   // RNE
  return (unsigned short)r;
}
__device__ __forceinline__ float bflo(unsigned u) {
  return __builtin_bit_cast(float, u << 16);
}
__device__ __forceinline__ float bfhi(unsigned u) {
  return __builtin_bit_cast(float, u & 0xffff0000u);
}

#define MFMA(acc, a, b) acc = __builtin_amdgcn_mfma_f32_16x16x32_bf16(a, b, acc, 0, 0, 0)

// DOT8: q = 4 u32 holding 8 bf16 (lo/hi pairs), hp = 8 floats
#define DOT8(a, q, hp) \
  a = fmaf(bflo(q.x), hp[0], a); a = fmaf(bfhi(q.x), hp[1], a); \
  a = fmaf(bflo(q.y), hp[2], a); a = fmaf(bfhi(q.y), hp[3], a); \
  a = fmaf(bflo(q.z), hp[4], a); a = fmaf(bfhi(q.z), hp[5], a); \
  a = fmaf(bflo(q.w), hp[6], a); a = fmaf(bfhi(q.w), hp[7], a);

// UNPS: 4 u32 (= 8 ushorts of a bf16 array) -> 8 floats
#define UNPS(dst, off, q) \
  dst[off+0] = bflo(q.x); dst[off+1] = bfhi(q.x); \
  dst[off+2] = bflo(q.y); dst[off+3] = bfhi(q.y); \
  dst[off+4] = bflo(q.z); dst[off+5] = bfhi(q.z); \
  dst[off+6] = bflo(q.w); dst[off+7] = bfhi(q.w);

// ---- fold GEMM: out[s][r][col] = sum_e A[s][e][r] * B[s][e][col], 256x256, K=256 ----
__global__ __launch_bounds__(256) void fold_gemm(const float* __restrict__ A, size_t sA,
                                                 const float* __restrict__ Bm, size_t sB,
                                                 float* __restrict__ out, size_t sO) {
  const int s = blockIdx.y, r0 = blockIdx.x * 32, col = threadIdx.x;
  A += (size_t)s * sA; Bm += (size_t)s * sB; out += (size_t)s * sO;
  float acc[32] = {};
  for (int e = 0; e < HDIM; ++e) {
    const float bvv = Bm[(size_t)e * HDIM + col];
#pragma unroll
    for (int r = 0; r < 32; ++r) acc[r] = fmaf(A[(size_t)e * HDIM + r0 + r], bvv, acc[r]);
  }
  for (int r = 0; r < 32; ++r) out[(size_t)(r0 + r) * HDIM + col] = acc[r];
}

// ---- pack gate weights [S][1024][Ksrc] into B-fragment layout, hi+lo bf16 ----
__global__ __launch_bounds__(64) void pack_hl(const float* __restrict__ src, int Ksrc, int ksT,
                                              bf16x8* __restrict__ outhi,
                                              bf16x8* __restrict__ outlo) {
  const int s = blockIdx.z, ks = blockIdx.y, nt = blockIdx.x;
  const int lane = threadIdx.x, l15 = lane & 15, quad = lane >> 4;
  const int n = nt * 16 + l15, kb = ks * 32 + quad * 8;
  const float* row = src + ((size_t)s * 1024 + n) * Ksrc;
  union { bf16x8 v; unsigned short e[8]; } h, l;
#pragma unroll
  for (int j = 0; j < 8; ++j) {
    const int k = kb + j;
    const float v = (k < Ksrc) ? row[k] : 0.f;
    const unsigned short hi = f2bf(v);
    h.e[j] = hi;
    l.e[j] = f2bf(v - bflo(hi));
  }
  const size_t idx = (((size_t)s * ksT + ks) * 64 + nt) * 64 + lane;
  outhi[idx] = h.v;
  outlo[idx] = l.v;
}

// ---- pack attention fold matrix P [S][256][256] into B-frag (single bf16), nt 0..15 ----
__global__ __launch_bounds__(64) void pack_s(const float* __restrict__ src, int ntOff,
                                             bf16x8* __restrict__ out) {
  const int s = blockIdx.z, ks = blockIdx.y, nt = blockIdx.x;
  const int lane = threadIdx.x, l15 = lane & 15, quad = lane >> 4;
  const int n = nt * 16 + l15, kb = ks * 32 + quad * 8;
  const float* row = src + ((size_t)s * 256 + n) * 256;
  union { bf16x8 v; unsigned short e[8]; } h;
#pragma unroll
  for (int j = 0; j < 8; ++j) h.e[j] = f2bf(row[kb + j]);
  out[(((size_t)s * 8 + ks) * 32 + ntOff + nt) * 64 + lane] = h.v;
}

// ---- fold vectors: kbv = Wk^T bq ; cbias = Wo bv + b_out ----
__global__ __launch_bounds__(256) void fold_vec2(const float* __restrict__ Win,
                                                 const float* __restrict__ bin,
                                                 const float* __restrict__ Wout,
                                                 const float* __restrict__ bout,
                                                 float* __restrict__ kbv,
                                                 float* __restrict__ cbias) {
  const int s = blockIdx.x, t = threadIdx.x;
  const float* bq = bin + s * 768;
  const float* bv = bin + s * 768 + 512;
  float a0 = 0.f, a1 = 0.f;
  for (int e = 0; e < 256; ++e) {
    a0 = fmaf(Win[((size_t)s * 768 + 256 + e) * 256 + t], bq[e], a0);
    a1 = fmaf(Wout[((size_t)s * 256 + t) * 256 + e], bv[e], a1);
  }
  kbv[s * 256 + t] = a0;
  cbias[s * 256 + t] = a1 + bout[s * 256 + t];
}

// ---- mvw = (wfo2^T . Wo) . Wv  WITHOUT materializing Mv = Wo.Wv ----
// (replaces transpose_k + fold_gemm(Mv) + fold_mvw: 134M MACs -> 131K MACs/stream)
__global__ __launch_bounds__(256) void fold_mvw2(const float* __restrict__ Win,
                                                 const float* __restrict__ Wout,
                                                 const float* __restrict__ Wfo,
                                                 float* __restrict__ mvw) {
  __shared__ float tmp[256];
  const int s = blockIdx.x, t = threadIdx.x;
  // tmp[e] = sum_o wfo2[o] * Wo[o][e]   (coalesced over t=e)
  float a = 0.f;
  for (int o = 0; o < 256; ++o)
    a = fmaf(Wfo[s * 512 + 256 + o], Wout[((size_t)s * 256 + o) * 256 + t], a);
  tmp[t] = a;
  __syncthreads();
  // mvw[k] = sum_e tmp[e] * Wv[e][k]    (coalesced over t=k)
  float b = 0.f;
  for (int e = 0; e < 256; ++e)
    b = fmaf(tmp[e], Win[((size_t)s * 768 + 512 + e) * 256 + t], b);
  mvw[s * 256 + t] = b;
}

// ---- fused: both bias folds (be, bd) in one launch ----
__global__ void fold_bias2(const float* __restrict__ a1, const float* __restrict__ b1,
                           float* __restrict__ o1,
                           const float* __restrict__ a2, const float* __restrict__ b2,
                           float* __restrict__ o2, int n) {
  int i = blockIdx.x * 256 + threadIdx.x;
  if (i < n) o1[i] = a1[i] + b1[i];
  else if (i < 2 * n) { int j = i - n; o2[j] = a2[j] + b2[j]; }
}

__global__ void build_decin(const float* __restrict__ x, const float* __restrict__ tgt,
                            float* __restrict__ dec_in) {
  int idx = blockIdx.x * 256 + threadIdx.x;
  if (idx >= LDEC * BATCH) return;
  int l = idx >> 10, b = idx & 1023;
  dec_in[idx] = (l == 0) ? x[(size_t)b * 96 * FDIM + 95 * FDIM]
                         : tgt[(size_t)b * LDEC + (l - 1)];
}

// =============== PHASE A: the recurrence, and ONLY the recurrence ===============
// R14 configuration — verified best (rec ~2100-2170 us). DO NOT PERTURB (R15/R16:
// any register-schedule perturbation regressed; this codegen is a local optimum).
__global__ __launch_bounds__(512) void rec_phase(
    const float* __restrict__ x,
    const bf16x8* __restrict__ WxH, const bf16x8* __restrict__ WxL,
    const bf16x8* __restrict__ WeH, const bf16x8* __restrict__ WeL,
    const bf16x8* __restrict__ WdH, const bf16x8* __restrict__ WdL,
    const float* __restrict__ be, const float* __restrict__ bd,
    const float* __restrict__ wihd, const float* __restrict__ Wfo,
    const float* __restrict__ decin,
    unsigned* __restrict__ hEnc,         // [t][s][b][e] packed hi|lo
    unsigned short* __restrict__ hDec,   // [l][s][b][e] bf16 hi
    float* __restrict__ hdPart)          // [l][s][b] = h_dec . wfo1 (fp32)
{
  __shared__ unsigned short hAhi[DBT * KA];   // 16.9 KB
  __shared__ unsigned short hAlo[DBT * KA];   // 16.9 KB
  __shared__ float beS[1024];                 // 4 KB
  __shared__ float bdS[1024];                 // 4 KB
  __shared__ float wdS[1024];                 // 4 KB
  __shared__ float wfoS[256];                 // 1 KB
  __shared__ float scrR[DBT * 8];             // 1 KB (hd partials)

  const int bid = blockIdx.x;
  const int s = bid & 7, b0 = (bid >> 3) * DBT;
  const int tid = threadIdx.x;
  const int w = tid >> 6, lane = tid & 63, l15 = lane & 15, quad = lane >> 4;

  for (int i = tid; i < DBT * KA; i += 512) { hAhi[i] = 0; hAlo[i] = 0; }
  for (int i = tid; i < 1024; i += 512) {
    beS[i] = be[s * 1024 + i];
    bdS[i] = bd[s * 1024 + i];
    wdS[i] = wihd[s * 1024 + i];
  }
  if (tid < 256) wfoS[tid] = Wfo[s * 512 + tid];

  float cst[2][2][4];
#pragma unroll
  for (int a = 0; a < 2; ++a)
#pragma unroll
    for (int b = 0; b < 2; ++b)
#pragma unroll
      for (int r = 0; r < 4; ++r) cst[a][b][r] = 0.f;

  const bf16x8* wxh = WxH + (size_t)s * 10 * 64 * 64;
  const bf16x8* wxl = WxL + (size_t)s * 10 * 64 * 64;
  const bf16x8* weh = WeH + (size_t)s * 8 * 64 * 64;
  const bf16x8* wel = WeL + (size_t)s * 8 * 64 * 64;
  const bf16x8* wdh = WdH + (size_t)s * 8 * 64 * 64;
  const bf16x8* wdl = WdL + (size_t)s * 8 * 64 * 64;

  __syncthreads();

  // ===================== encoder =====================
  for (int t = 0; t < TENC; ++t) {
    f32x4 acc[2][2][4];
#pragma unroll
    for (int mt = 0; mt < 2; ++mt)
#pragma unroll
      for (int st = 0; st < 2; ++st)
#pragma unroll
        for (int c = 0; c < 4; ++c) acc[mt][st][c] = (f32x4){0.f, 0.f, 0.f, 0.f};

    const size_t xoff = (size_t)(s * TENC + t) * FDIM;
    for (int ks = 0; ks < 10; ++ks) {
      bf16x8 axh[2], axl[2];
#pragma unroll
      for (int mt = 0; mt < 2; ++mt) {
        const f32x4* xr = (const f32x4*)(x + (size_t)(b0 + 16 * mt + l15) * (96 * FDIM)
                                         + xoff + ks * 32 + quad * 8);
        const f32x4 v0 = __builtin_nontemporal_load(xr);
        f32x4 v1;
        if (ks == 9 && quad == 3) v1 = (f32x4){0.f, 0.f, 0.f, 0.f};
        else v1 = __builtin_nontemporal_load(xr + 1);
        float vv[8];
#pragma unroll
        for (int j = 0; j < 4; ++j) { vv[j] = v0[j]; vv[4 + j] = v1[j]; }
        union { bf16x8 v; unsigned short e[8]; } uh, ul;
#pragma unroll
        for (int j = 0; j < 8; ++j) {
          const unsigned short hi = f2bf(vv[j]);
          uh.e[j] = hi;
          ul.e[j] = f2bf(vv[j] - bflo(hi));
        }
        axh[mt] = uh.v; axl[mt] = ul.v;
      }
#pragma unroll
      for (int st = 0; st < 2; ++st)
#pragma unroll
        for (int c = 0; c < 4; ++c) {
          const int nt = c * 16 + 2 * w + st;
          const bf16x8 bh = wxh[(ks * 64 + nt) * 64 + lane];
          const bf16x8 bl = wxl[(ks * 64 + nt) * 64 + lane];
          MFMA(acc[0][st][c], axh[0], bh); MFMA(acc[0][st][c], axh[0], bl); MFMA(acc[0][st][c], axl[0], bh);
          MFMA(acc[1][st][c], axh[1], bh); MFMA(acc[1][st][c], axh[1], bl); MFMA(acc[1][st][c], axl[1], bh);
        }
    }
#pragma unroll 2
    for (int ks = 0; ks < 8; ++ks) {
      bf16x8 ah[2], al[2];
#pragma unroll
      for (int mt = 0; mt < 2; ++mt) {
        const int ao = (16 * mt + l15) * KA + ks * 32 + quad * 8;
        ah[mt] = *(const bf16x8*)&hAhi[ao];
        al[mt] = *(const bf16x8*)&hAlo[ao];
      }
#pragma unroll
      for (int st = 0; st < 2; ++st)
#pragma unroll
        for (int c = 0; c < 4; ++c) {
          const int nt = c * 16 + 2 * w + st;
          const bf16x8 bh = weh[(ks * 64 + nt) * 64 + lane];
          const bf16x8 bl = wel[(ks * 64 + nt) * 64 + lane];
          MFMA(acc[0][st][c], ah[0], bh); MFMA(acc[0][st][c], ah[0], bl); MFMA(acc[0][st][c], al[0], bh);
          MFMA(acc[1][st][c], ah[1], bh); MFMA(acc[1][st][c], ah[1], bl); MFMA(acc[1][st][c], al[1], bh);
        }
    }
    // pointwise LSTM -- gate biases from LDS table
    float hv[2][2][4];
#pragma unroll
    for (int st = 0; st < 2; ++st) {
      const int J0 = 32 * w + 16 * st + l15;
      const float g0 = beS[J0];
      const float g1 = beS[256 + J0];
      const float g2 = beS[512 + J0];
      const float g3 = beS[768 + J0];
#pragma unroll
      for (int mt = 0; mt < 2; ++mt)
#pragma unroll
        for (int reg = 0; reg < 4; ++reg) {
          const float gi = sigf(acc[mt][st][0][reg] + g0);
          const float gf = sigf(acc[mt][st][1][reg] + g1);
          const float gg = tanhf(acc[mt][st][2][reg] + g2);
          const float go = sigf(acc[mt][st][3][reg] + g3);
          const float cn = fmaf(gf, cst[mt][st][reg], gi * gg);
          cst[mt][st][reg] = cn;
          hv[mt][st][reg] = go * tanhf(cn);
        }
    }
    __syncthreads();
#pragma unroll
    for (int mt = 0; mt < 2; ++mt)
#pragma unroll
      for (int st = 0; st < 2; ++st)
#pragma unroll
        for (int reg = 0; reg < 4; ++reg) {
          const int R = 16 * mt + 4 * quad + reg;
          const int J = 32 * w + 16 * st + l15;
          const float v = hv[mt][st][reg];
          const unsigned short hi = f2bf(v);
          const unsigned short lo = f2bf(v - bflo(hi));
          hAhi[R * KA + J] = hi;
          hAlo[R * KA + J] = lo;
          __builtin_nontemporal_store((unsigned)hi | ((unsigned)lo << 16),
              &hEnc[((size_t)(t * S8 + s) * BATCH + b0 + R) * HDIM + J]);
        }
    __syncthreads();
  }

  // ===================== decoder (LSTM only + fp32 hd dot) =====================
  for (int l = 0; l < LDEC; ++l) {
    f32x4 acc[2][2][4];
#pragma unroll
    for (int mt = 0; mt < 2; ++mt)
#pragma unroll
      for (int st = 0; st < 2; ++st)
#pragma unroll
        for (int c = 0; c < 4; ++c) acc[mt][st][c] = (f32x4){0.f, 0.f, 0.f, 0.f};

#pragma unroll 2
    for (int ks = 0; ks < 8; ++ks) {
      bf16x8 ah[2], al[2];
#pragma unroll
      for (int mt = 0; mt < 2; ++mt) {
        const int ao = (16 * mt + l15) * KA + ks * 32 + quad * 8;
        ah[mt] = *(const bf16x8*)&hAhi[ao];
        al[mt] = *(const bf16x8*)&hAlo[ao];
      }
#pragma unroll
      for (int st = 0; st < 2; ++st)
#pragma unroll
        for (int c = 0; c < 4; ++c) {
          const int nt = c * 16 + 2 * w + st;
          const bf16x8 bh = wdh[(ks * 64 + nt) * 64 + lane];
          const bf16x8 bl = wdl[(ks * 64 + nt) * 64 + lane];
          MFMA(acc[0][st][c], ah[0], bh); MFMA(acc[0][st][c], ah[0], bl); MFMA(acc[0][st][c], al[0], bh);
          MFMA(acc[1][st][c], ah[1], bh); MFMA(acc[1][st][c], ah[1], bl); MFMA(acc[1][st][c], al[1], bh);
        }
    }
    // pointwise LSTM -- bd/wd from LDS tables
    float hv[2][2][4];
#pragma unroll
    for (int st = 0; st < 2; ++st) {
      const int J0 = 32 * w + 16 * st + l15;
      const float b0g = bdS[J0];
      const float b1g = bdS[256 + J0];
      const float b2g = bdS[512 + J0];
      const float b3g = bdS[768 + J0];
      const float w0g = wdS[J0];
      const float w1g = wdS[256 + J0];
      const float w2g = wdS[512 + J0];
      const float w3g = wdS[768 + J0];
#pragma unroll
      for (int mt = 0; mt < 2; ++mt)
#pragma unroll
        for (int reg = 0; reg < 4; ++reg) {
          const int R = 16 * mt + 4 * quad + reg;
          const float it = decin[(size_t)l * BATCH + b0 + R];
          const float gi = sigf(fmaf(it, w0g, acc[mt][st][0][reg] + b0g));
          const float gf = sigf(fmaf(it, w1g, acc[mt][st][1][reg] + b1g));
          const float gg = tanhf(fmaf(it, w2g, acc[mt][st][2][reg] + b2g));
          const float go = sigf(fmaf(it, w3g, acc[mt][st][3][reg] + b3g));
          const float cn = fmaf(gf, cst[mt][st][reg], gi * gg);
          cst[mt][st][reg] = cn;
          hv[mt][st][reg] = go * tanhf(cn);
        }
    }
    __syncthreads();
#pragma unroll
    for (int mt = 0; mt < 2; ++mt)
#pragma unroll
      for (int st = 0; st < 2; ++st)
#pragma unroll
        for (int reg = 0; reg < 4; ++reg) {
          const int R = 16 * mt + 4 * quad + reg;
          const int J = 32 * w + 16 * st + l15;
          const float v = hv[mt][st][reg];
          const unsigned short hi = f2bf(v);
          hAhi[R * KA + J] = hi;
          hAlo[R * KA + J] = f2bf(v - bflo(hi));
          __builtin_nontemporal_store(hi,
              &hDec[((size_t)(l * S8 + s) * BATCH + b0 + R) * HDIM + J]);
        }
    // hd = h . wfo1 in fp32 from registers
    {
      float part[8];
#pragma unroll
      for (int mt = 0; mt < 2; ++mt)
#pragma unroll
        for (int reg = 0; reg < 4; ++reg) {
          const int J0 = 32 * w + l15;
          part[mt * 4 + reg] = hv[mt][0][reg] * wfoS[J0] + hv[mt][1][reg] * wfoS[J0 + 16];
        }
#pragma unroll
      for (int i = 0; i < 8; ++i) {
        float v = part[i];
        v += __shfl_xor(v, 1, 16);
        v += __shfl_xor(v, 2, 16);
        v += __shfl_xor(v, 4, 16);
        v += __shfl_xor(v, 8, 16);
        part[i] = v;
      }
      if (l15 == 0) {
#pragma unroll
        for (int mt = 0; mt < 2; ++mt)
#pragma unroll
          for (int reg = 0; reg < 4; ++reg)
            scrR[(16 * mt + 4 * quad + reg) * 8 + w] = part[mt * 4 + reg];
      }
    }
    __syncthreads();
    if (tid < DBT) {
      float a = 0.f;
#pragma unroll
      for (int p = 0; p < 8; ++p) a += scrR[tid * 8 + p];
      hdPart[((size_t)l * S8 + s) * BATCH + b0 + tid] = a;
    }
    // no extra barrier: scrR's next write is after next iter's first sync
  }
}

// =============== PHASE B: attention + output, 1024 threads (R18) ===============
__global__ __launch_bounds__(1024) void attn_phase(
    const unsigned* __restrict__ hEnc, const unsigned short* __restrict__ hDec,
    const bf16x8* __restrict__ AMvF,
    const float* __restrict__ kbv, const float* __restrict__ cbias,
    const float* __restrict__ mvw,
    const float* __restrict__ Wfo, const float* __restrict__ bfo,
    const float* __restrict__ hdPart,
    float* __restrict__ douts)
{
  __shared__ unsigned short kpL[TENC][16][KA];   // 101.4 KB
  __shared__ float scr2[2 * 16 * TENC * 33];     // 50.7 KB (score partials, 2 l)
  __shared__ float sc[2][16][TENC];              // 1.5 KB
  __shared__ float kbs[TENC][16];                // 0.75 KB
  __shared__ float vw[TENC][16];                 // 0.75 KB

  const int s = blockIdx.y, b0 = blockIdx.x * 16;
  const int tid = threadIdx.x;
  const int w = tid >> 6, lane = tid & 63, l15 = lane & 15, quad = lane >> 4;

  const bf16x8* amv = AMvF + (size_t)s * 8 * 32 * 64;
  const float* kvv = kbv + s * 256;
  const float* mvv = mvw + s * 256;
  const float* cbs = cbias + s * 256;
  const float* wfo = Wfo + s * 512;
  const float bfos = bfo[s];

  float cw = 0.f;
  for (int e = 0; e < 256; ++e) cw = fmaf(cbs[e], wfo[256 + e], cw);

  // --- kp[t] = P . h_enc[t] via MFMA; 16 waves, wave w owns nt = w ---
  for (int t = 0; t < TENC; ++t) {
    f32x4 acc = (f32x4){0.f, 0.f, 0.f, 0.f};
    for (int ks = 0; ks < 8; ++ks) {
      const unsigned* hp = hEnc + ((size_t)(t * S8 + s) * BATCH + b0 + l15) * HDIM
                         + ks * 32 + quad * 8;
      union { bf16x8 v; unsigned short e[8]; } uh, ul;
#pragma unroll
      for (int j = 0; j < 8; ++j) {
        const unsigned u = hp[j];
        uh.e[j] = (unsigned short)u;
        ul.e[j] = (unsigned short)(u >> 16);
      }
      const bf16x8 b = amv[(ks * 32 + w) * 64 + lane];
      MFMA(acc, uh.v, b); MFMA(acc, ul.v, b);
    }
#pragma unroll
    for (int reg = 0; reg < 4; ++reg)
      kpL[t][4 * quad + reg][w * 16 + l15] = f2bf(acc[reg]);
  }

  // --- kbs / vw folds: one wave per row, 64-lane shfl reduce, no barriers ---
  {
    const int row = tid >> 6;   // 0..15
    const int p = lane;         // 0..63, 4 elements each
    for (int t = 0; t < TENC; ++t) {
      const unsigned* hp = hEnc + ((size_t)(t * S8 + s) * BATCH + b0 + row) * HDIM + p * 4;
      float a = 0.f, bv = 0.f;
#pragma unroll
      for (int j = 0; j < 4; ++j) {
        const unsigned u = hp[j];
        const float h = bflo(u) + bfhi(u);
        a = fmaf(kvv[p * 4 + j], h, a);
        bv = fmaf(mvv[p * 4 + j], h, bv);
      }
#pragma unroll
      for (int off = 1; off < 64; off <<= 1) {
        a += __shfl_xor(a, off, 64);
        bv += __shfl_xor(bv, off, 64);
      }
      if (lane == 0) { kbs[t][row] = a; vw[t][row] = bv; }
    }
  }
  __syncthreads();   // kpL + kbs + vw ready

  // --- l-loop: 2 decoder steps per iteration ---
  for (int li = 0; li < LDEC / 2; ++li) {
    const int lh = tid >> 9;          // 0 or 1
    const int l = li * 2 + lh;
    const int t2 = tid & 511;
    const int row = t2 & 15, pp = t2 >> 4;   // pp 0..31, chunks of 8
    float hh[8];
    {
      const unsigned short* hp = hDec + ((size_t)(l * S8 + s) * BATCH + b0 + row) * HDIM + pp * 8;
      const uint4 q = *(const uint4*)hp;
      UNPS(hh, 0, q);
    }
#pragma unroll 2
    for (int t = 0; t < TENC; ++t) {
      const uint4 q0 = *(const uint4*)&kpL[t][row][pp * 8];
      float a = 0.f;
      const float* hp8 = hh;
      DOT8(a, q0, hp8);
      scr2[((lh * 16 + row) * TENC + t) * 33 + pp] = a;
    }
    __syncthreads();
    if (t2 < 192) {
      const int r2 = t2 & 15, tt = t2 >> 4;
      float a = kbs[tt][r2];
#pragma unroll
      for (int p2 = 0; p2 < 32; ++p2) a += scr2[((lh * 16 + r2) * TENC + tt) * 33 + p2];
      sc[lh][r2][tt] = a * SCALE_ATTN;
    }
    __syncthreads();
    if (t2 < 16) {
      float m = sc[lh][t2][0];
#pragma unroll
      for (int tt = 1; tt < TENC; ++tt) m = fmaxf(m, sc[lh][t2][tt]);
      float e[TENC], sum = 0.f;
#pragma unroll
      for (int tt = 0; tt < TENC; ++tt) { e[tt] = expf(sc[lh][t2][tt] - m); sum += e[tt]; }
      const float inv = 1.0f / sum;
      float av = 0.f;
#pragma unroll
      for (int tt = 0; tt < TENC; ++tt) av = fmaf(e[tt] * inv, vw[tt][t2], av);
      const float hd = hdPart[((size_t)l * S8 + s) * BATCH + b0 + t2];
      douts[((size_t)l * S8 + s) * BATCH + b0 + t2] = hd + av + cw + bfos;
    }
    __syncthreads();
  }
}

// ---------------- final fc over streams ----------------
__global__ void final_fc(const float* __restrict__ douts, const float* __restrict__ Wfc,
                         const float* __restrict__ bfc, float* __restrict__ out) {
  int idx = blockIdx.x * 256 + threadIdx.x;
  if (idx >= BATCH * LDEC) return;
  int b = idx / LDEC, l = idx - b * LDEC;
  float a = bfc[0];
#pragma unroll
  for (int s = 0; s < S8; ++s)
    a = fmaf(douts[((size_t)l * S8 + s) * BATCH + b], Wfc[s], a);
  out[idx] = a;
}

extern "C" void kernel_launch(void* const* d_in, const int* in_sizes, int n_in,
                              void* d_out, int out_size, void* d_ws, size_t ws_size,
                              hipStream_t stream) {
  const float* x          = (const float*)d_in[0];
  const float* tgt        = (const float*)d_in[1];
  const float* W_ih_e     = (const float*)d_in[2];
  const float* W_hh_e     = (const float*)d_in[3];
  const float* b_ih_e     = (const float*)d_in[4];
  const float* b_hh_e     = (const float*)d_in[5];
  const float* W_ih_d     = (const float*)d_in[6];
  const float* W_hh_d     = (const float*)d_in[7];
  const float* b_ih_d     = (const float*)d_in[8];
  const float* b_hh_d     = (const float*)d_in[9];
  const float* W_in_attn  = (const float*)d_in[10];
  const float* b_in_attn  = (const float*)d_in[11];
  const float* W_out_attn = (const float*)d_in[12];
  const float* b_out_attn = (const float*)d_in[13];
  const float* W_fcout    = (const float*)d_in[14];
  const float* b_fcout    = (const float*)d_in[15];
  const float* W_fc       = (const float*)d_in[16];
  const float* b_fc       = (const float*)d_in[17];

  char* wsb = (char*)d_ws;
  size_t off = 0;
  auto alloc = [&](size_t bytes) {
    void* p = wsb + off; off += (bytes + 255) & ~(size_t)255; return p;
  };
  float*  douts = (float*)alloc((size_t)LDEC * S8 * BATCH * 4);
  float*  decin = (float*)alloc((size_t)LDEC * BATCH * 4);
  float*  hdPart= (float*)alloc((size_t)LDEC * S8 * BATCH * 4);
  float*  Pmat  = (float*)alloc((size_t)S8 * 256 * 256 * 4);
  bf16x8* WxH   = (bf16x8*)alloc((size_t)S8 * 10 * 64 * 64 * 16);
  bf16x8* WxL   = (bf16x8*)alloc((size_t)S8 * 10 * 64 * 64 * 16);
  bf16x8* WeH   = (bf16x8*)alloc((size_t)S8 * 8 * 64 * 64 * 16);
  bf16x8* WeL   = (bf16x8*)alloc((size_t)S8 * 8 * 64 * 64 * 16);
  bf16x8* WdH   = (bf16x8*)alloc((size_t)S8 * 8 * 64 * 64 * 16);
  bf16x8* WdL   = (bf16x8*)alloc((size_t)S8 * 8 * 64 * 64 * 16);
  bf16x8* AMvF  = (bf16x8*)alloc((size_t)S8 * 8 * 32 * 64 * 16);
  float*  kbv   = (float*)alloc((size_t)S8 * 256 * 4);
  float*  cbias = (float*)alloc((size_t)S8 * 256 * 4);
  float*  mvw   = (float*)alloc((size_t)S8 * 256 * 4);
  float*  beF   = (float*)alloc((size_t)S8 * 1024 * 4);
  float*  bdF   = (float*)alloc((size_t)S8 * 1024 * 4);
  unsigned* hEnc = (unsigned*)alloc((size_t)TENC * S8 * BATCH * HDIM * 4);             // 100.7 MB
  unsigned short* hDec = (unsigned short*)alloc((size_t)LDEC * S8 * BATCH * HDIM * 2); // 201.3 MB
  if (off > ws_size) {
    fprintf(stderr, "kernel_launch: ws too small: need %zu bytes, have %zu\n", off, ws_size);
    return;
  }

  // ---- one-time weight preparation ----
  // P[n][k] = sum_e Wq[e][n] Wk[e][k]
  fold_gemm<<<dim3(8, S8), 256, 0, stream>>>(W_in_attn, (size_t)768 * 256,
                                             W_in_attn + 256 * 256, (size_t)768 * 256,
                                             Pmat, (size_t)256 * 256);
  pack_hl<<<dim3(64, 10, S8), 64, 0, stream>>>(W_ih_e, FDIM, 10, WxH, WxL);
  pack_hl<<<dim3(64, 8, S8), 64, 0, stream>>>(W_hh_e, 256, 8, WeH, WeL);
  pack_hl<<<dim3(64, 8, S8), 64, 0, stream>>>(W_hh_d, 256, 8, WdH, WdL);
  pack_s<<<dim3(16, 8, S8), 64, 0, stream>>>(Pmat, 0, AMvF);
  fold_vec2<<<S8, 256, 0, stream>>>(W_in_attn, b_in_attn, W_out_attn, b_out_attn, kbv, cbias);
  fold_mvw2<<<S8, 256, 0, stream>>>(W_in_attn, W_out_attn, W_fcout, mvw);
  fold_bias2<<<(2 * S8 * 1024 + 255) / 256, 256, 0, stream>>>(
      b_ih_e, b_hh_e, beF, b_ih_d, b_hh_d, bdF, S8 * 1024);
  build_decin<<<(LDEC * BATCH + 255) / 256, 256, 0, stream>>>(x, tgt, decin);

  // Phase A: the recurrence only (grid 256, 512 thr — R14 verified best)
  rec_phase<<<256, 512, 0, stream>>>(
      x, WxH, WxL, WeH, WeL, WdH, WdL, beF, bdF, W_ih_d, W_fcout, decin,
      hEnc, hDec, hdPart);

  // Phase B: attention + outputs (1024 thr, 2 l/iter, wave-reduced folds)
  attn_phase<<<dim3(64, S8), 1024, 0, stream>>>(
      hEnc, hDec, AMvF, kbv, cbias, mvw, W_fcout, b_fcout, hdPart, douts);

  final_fc<<<(BATCH * LDEC + 255) / 256, 256, 0, stream>>>(douts, W_fc, b_fc, (float*)d_out);
}